// Round 3
// baseline (1355.849 us; speedup 1.0000x reference)
//
#include <hip/hip_runtime.h>

#define DEVINL __device__ __forceinline__

typedef __bf16 bf16x8 __attribute__((ext_vector_type(8)));
typedef float  f32x4  __attribute__((ext_vector_type(4)));

constexpr int KK = 4096;        // K
constexpr int NN = 11008;       // N
constexpr int NG = 32;          // K / group_size(128)
constexpr int BM = 128, BN = 128, BK = 32;

DEVINL unsigned short f2bf(float f){
  union { float f; unsigned u; } v; v.f = f;
  unsigned r = v.u + 0x7FFF + ((v.u >> 16) & 1);   // RNE; inputs finite here
  return (unsigned short)(r >> 16);
}

// ---------------- pre-kernel: dequant W (int4-in-int32) -> bf16 [N][K] ----
// thread = 4 int32 (= 8 k-values) -> one 16B store. fp32 scales.
__global__ __launch_bounds__(256) void k_dequant(const int* __restrict__ W,
                                                 const float* __restrict__ S,
                                                 unsigned short* __restrict__ WB){
  int t = blockIdx.x * 256 + threadIdx.x;     // quad id; total NN*(KK/8)
  int row = t >> 9;                           // 512 quads per N-row
  int kp0 = (t & 511) << 2;                   // starting int32 (k-pair) in row
  int g   = kp0 >> 6;                         // group = kp0*2/128
  float s = S[row * NG + g];
  const int4 p = reinterpret_cast<const int4*>(W)[t];
  const int* pb = reinterpret_cast<const int*>(&p);
  unsigned q[4];
  #pragma unroll
  for (int i = 0; i < 4; ++i){
    int b = pb[i];
    float lo = ((float)(b & 15)        - 8.0f) * s;   // even k
    float hi = ((float)((b >> 4) & 15) - 8.0f) * s;   // odd k
    q[i] = (unsigned)f2bf(lo) | ((unsigned)f2bf(hi) << 16);
  }
  reinterpret_cast<int4*>(WB)[t] = make_int4((int)q[0], (int)q[1], (int)q[2], (int)q[3]);
}

// ---------------- main GEMM: A fp32 [M][K], B bf16 [N][K] (B^T form) ------
// m97 tile geometry, vanilla reg-staging; A converted fp32->bf16 at ds_write.
__global__ __launch_bounds__(256) void k_gemm_ws(const float* __restrict__ A,
                                                 const unsigned short* __restrict__ B,
                                                 const float* __restrict__ Bias,
                                                 float* __restrict__ C){
  __shared__ unsigned short As[2][BM][BK];
  __shared__ unsigned short Bs[2][BN][BK];
  const int tid = threadIdx.x;
  const int NT = NN / BN;                       // 86
  const int mt = blockIdx.x / NT, nt = blockIdx.x % NT;
  const float*          Ab = A + (size_t)mt * BM * KK;
  const unsigned short* Bb = B + (size_t)nt * BN * KK;
  const int lane = tid & 63, wid = tid >> 6;
  const int wm = wid >> 1, wn = wid & 1;
  const int lr = lane & 15, lk = (lane >> 4) << 3;

  auto ld = [&](int kt, float4* ra, int4* rb){
    #pragma unroll
    for (int r = 0; r < 2; ++r){
      int c = r * 256 + tid, row = c >> 2, k0 = (c & 3) << 3;
      const float* src = Ab + (size_t)row * KK + kt * BK + k0;
      ra[2*r]   = *reinterpret_cast<const float4*>(src);
      ra[2*r+1] = *reinterpret_cast<const float4*>(src + 4);
      rb[r] = *reinterpret_cast<const int4*>(Bb + (size_t)row * KK + kt * BK + k0);
    }
  };
  auto st = [&](int buf, const float4* ra, const int4* rb){
    #pragma unroll
    for (int r = 0; r < 2; ++r){
      int c = r * 256 + tid, row = c >> 2, k0 = (c & 3) << 3;
      unsigned q[4];
      #pragma unroll
      for (int i = 0; i < 4; ++i){
        float lo = ra[2*r + (i >> 1)][(i & 1) * 2];
        float hi = ra[2*r + (i >> 1)][(i & 1) * 2 + 1];
        q[i] = (unsigned)f2bf(lo) | ((unsigned)f2bf(hi) << 16);
      }
      *reinterpret_cast<int4*>(&As[buf][row][k0]) =
          make_int4((int)q[0], (int)q[1], (int)q[2], (int)q[3]);
      *reinterpret_cast<int4*>(&Bs[buf][row][k0]) = rb[r];
    }
  };

  f32x4 acc[4][4] = {};
  {
    float4 ra[4]; int4 rb[2];
    ld(0, ra, rb);
    st(0, ra, rb);
  }
  __syncthreads();
  const int KT = KK / BK;                      // 128
  for (int kt = 0; kt < KT; ++kt){
    int cur = kt & 1;
    float4 na[4]; int4 nb[2];
    if (kt + 1 < KT) ld(kt + 1, na, nb);       // issue loads early (hide under MFMA)
    bf16x8 af[4], bfr[4];
    #pragma unroll
    for (int i = 0; i < 4; ++i)
      af[i] = *reinterpret_cast<const bf16x8*>(&As[cur][wm*64 + i*16 + lr][lk]);
    #pragma unroll
    for (int i = 0; i < 4; ++i)
      bfr[i] = *reinterpret_cast<const bf16x8*>(&Bs[cur][wn*64 + i*16 + lr][lk]);
    #pragma unroll
    for (int i = 0; i < 4; ++i)
      #pragma unroll
      for (int j = 0; j < 4; ++j)
        acc[i][j] = __builtin_amdgcn_mfma_f32_16x16x32_bf16(af[i], bfr[j], acc[i][j], 0, 0, 0);
    if (kt + 1 < KT) st(cur ^ 1, na, nb);      // write-late into the other buffer
    __syncthreads();
  }
  const int cm = mt * BM + wm * 64;
  const int cn = nt * BN + wn * 64;
  float bv[4];
  #pragma unroll
  for (int j = 0; j < 4; ++j) bv[j] = Bias[cn + j*16 + lr];
  #pragma unroll
  for (int i = 0; i < 4; ++i)
    #pragma unroll
    for (int j = 0; j < 4; ++j)
      #pragma unroll
      for (int r = 0; r < 4; ++r){
        size_t rr = (size_t)(cm + i*16 + (lane >> 4)*4 + r);
        C[rr * NN + (cn + j*16 + lr)] = acc[i][j][r] + bv[j];
      }
}

// ---------------- fallback: fused dequant in the GEMM staging -------------
__global__ __launch_bounds__(256) void k_gemm_fused(const float* __restrict__ A,
                                                    const int* __restrict__ W,
                                                    const float* __restrict__ S,
                                                    const float* __restrict__ Bias,
                                                    float* __restrict__ C){
  __shared__ unsigned short As[2][BM][BK];
  __shared__ unsigned short Bs[2][BN][BK];
  const int tid = threadIdx.x;
  const int NT = NN / BN;
  const int mt = blockIdx.x / NT, nt = blockIdx.x % NT;
  const float* Ab = A + (size_t)mt * BM * KK;
  const int lane = tid & 63, wid = tid >> 6;
  const int wm = wid >> 1, wn = wid & 1;
  const int lr = lane & 15, lk = (lane >> 4) << 3;

  auto ld = [&](int kt, float4* ra, unsigned (*qb)[4]){
    int g = kt >> 2;
    #pragma unroll
    for (int r = 0; r < 2; ++r){
      int c = r * 256 + tid, row = c >> 2, kq = c & 3;
      int n = nt * BN + row;
      const int4 p = *reinterpret_cast<const int4*>(W + (size_t)n * (KK/2) + kt * (BK/2) + kq * 4);
      const int* pb = reinterpret_cast<const int*>(&p);
      float s = S[n * NG + g];
      #pragma unroll
      for (int i = 0; i < 4; ++i){
        int b = pb[i];
        float lo = ((float)(b & 15)        - 8.0f) * s;
        float hi = ((float)((b >> 4) & 15) - 8.0f) * s;
        qb[r][i] = (unsigned)f2bf(lo) | ((unsigned)f2bf(hi) << 16);
      }
      const float* src = Ab + (size_t)row * KK + kt * BK + (kq << 3);
      ra[2*r]   = *reinterpret_cast<const float4*>(src);
      ra[2*r+1] = *reinterpret_cast<const float4*>(src + 4);
    }
  };
  auto st = [&](int buf, const float4* ra, const unsigned (*qb)[4]){
    #pragma unroll
    for (int r = 0; r < 2; ++r){
      int c = r * 256 + tid, row = c >> 2, kq = c & 3;
      *reinterpret_cast<int4*>(&Bs[buf][row][kq << 3]) =
          make_int4((int)qb[r][0], (int)qb[r][1], (int)qb[r][2], (int)qb[r][3]);
      unsigned q[4];
      #pragma unroll
      for (int i = 0; i < 4; ++i){
        float lo = ra[2*r + (i >> 1)][(i & 1) * 2];
        float hi = ra[2*r + (i >> 1)][(i & 1) * 2 + 1];
        q[i] = (unsigned)f2bf(lo) | ((unsigned)f2bf(hi) << 16);
      }
      *reinterpret_cast<int4*>(&As[buf][row][kq << 3]) =
          make_int4((int)q[0], (int)q[1], (int)q[2], (int)q[3]);
    }
  };

  f32x4 acc[4][4] = {};
  {
    float4 ra[4]; unsigned qb[2][4];
    ld(0, ra, qb);
    st(0, ra, qb);
  }
  __syncthreads();
  const int KT = KK / BK;
  for (int kt = 0; kt < KT; ++kt){
    int cur = kt & 1;
    float4 na[4]; unsigned nq[2][4];
    if (kt + 1 < KT) ld(kt + 1, na, nq);
    bf16x8 af[4], bfr[4];
    #pragma unroll
    for (int i = 0; i < 4; ++i)
      af[i] = *reinterpret_cast<const bf16x8*>(&As[cur][wm*64 + i*16 + lr][lk]);
    #pragma unroll
    for (int i = 0; i < 4; ++i)
      bfr[i] = *reinterpret_cast<const bf16x8*>(&Bs[cur][wn*64 + i*16 + lr][lk]);
    #pragma unroll
    for (int i = 0; i < 4; ++i)
      #pragma unroll
      for (int j = 0; j < 4; ++j)
        acc[i][j] = __builtin_amdgcn_mfma_f32_16x16x32_bf16(af[i], bfr[j], acc[i][j], 0, 0, 0);
    if (kt + 1 < KT) st(cur ^ 1, na, nq);
    __syncthreads();
  }
  const int cm = mt * BM + wm * 64;
  const int cn = nt * BN + wn * 64;
  float bv[4];
  #pragma unroll
  for (int j = 0; j < 4; ++j) bv[j] = Bias[cn + j*16 + lr];
  #pragma unroll
  for (int i = 0; i < 4; ++i)
    #pragma unroll
    for (int j = 0; j < 4; ++j)
      #pragma unroll
      for (int r = 0; r < 4; ++r){
        size_t rr = (size_t)(cm + i*16 + (lane >> 4)*4 + r);
        C[rr * NN + (cn + j*16 + lr)] = acc[i][j][r] + bv[j];
      }
}

extern "C" void kernel_launch(void* const* d_in, const int* in_sizes, int n_in,
                              void* d_out, int out_size, void* d_ws, size_t ws_size,
                              hipStream_t stream){
  const float* x    = (const float*)d_in[0];   // fp32 [M][K] (fp16 ref -> float)
  const int*   w    = (const int*)d_in[1];     // [N][K/2] packed bytes
  const float* s    = (const float*)d_in[2];   // fp32 [N][NG]
  const float* bias = (const float*)d_in[3];   // fp32 [N]
  float* out = (float*)d_out;                  // fp32 [M][N]
  const int M = in_sizes[0] / KK;              // 8192
  const int grid = (M / BM) * (NN / BN);       // 64*86 = 5504
  const size_t need = (size_t)NN * KK * 2;     // 90.2 MB for bf16 W
  if (ws_size >= need){
    unsigned short* wb = (unsigned short*)d_ws;
    const int dq_blocks = (NN * (KK / 8)) / 256;   // 22016
    k_dequant<<<dq_blocks, 256, 0, stream>>>(w, s, wb);
    k_gemm_ws<<<grid, 256, 0, stream>>>(x, wb, bias, out);
  } else {
    k_gemm_fused<<<grid, 256, 0, stream>>>(x, w, s, bias, out);
  }
}

// Round 4
// 1094.777 us; speedup vs baseline: 1.2385x; 1.2385x over previous
//
#include <hip/hip_runtime.h>

#define DEVINL __device__ __forceinline__

typedef __bf16 bf16x8 __attribute__((ext_vector_type(8)));
typedef float  f32x4  __attribute__((ext_vector_type(4)));

constexpr int KK = 4096;        // K
constexpr int NN = 11008;       // N
constexpr int NG = 32;          // K / group_size(128)
constexpr int BM = 128, BN = 128, BK = 32;

DEVINL unsigned short f2bf(float f){
  union { float f; unsigned u; } v; v.f = f;
  unsigned r = v.u + 0x7FFF + ((v.u >> 16) & 1);   // RNE; inputs finite here
  return (unsigned short)(r >> 16);
}
DEVINL unsigned pack2(float lo, float hi){
  return (unsigned)f2bf(lo) | ((unsigned)f2bf(hi) << 16);
}
DEVINL void gload16(const void* g, void* l){
  __builtin_amdgcn_global_load_lds(
      (const __attribute__((address_space(1))) void*)g,
      (__attribute__((address_space(3))) void*)l, 16, 0, 0);
}

// ---------------- pre-kernel 1: dequant W (int4-in-int32) -> bf16 [N][K] --
// thread = 4 int32 (= 8 k-values) -> one 16B store. Verified round 3.
__global__ __launch_bounds__(256) void k_dequant(const int* __restrict__ W,
                                                 const float* __restrict__ S,
                                                 unsigned short* __restrict__ WB){
  int t = blockIdx.x * 256 + threadIdx.x;     // quad id; total NN*(KK/8)
  int row = t >> 9;                           // 512 quads per N-row
  int kp0 = (t & 511) << 2;                   // starting int32 (k-pair) in row
  int g   = kp0 >> 6;                         // group = kp0*2/128
  float s = S[row * NG + g];
  const int4 p = reinterpret_cast<const int4*>(W)[t];
  const int* pb = reinterpret_cast<const int*>(&p);
  unsigned q[4];
  #pragma unroll
  for (int i = 0; i < 4; ++i){
    int b = pb[i];
    float lo = ((float)(b & 15)        - 8.0f) * s;   // even k
    float hi = ((float)((b >> 4) & 15) - 8.0f) * s;   // odd k
    q[i] = pack2(lo, hi);
  }
  reinterpret_cast<int4*>(WB)[t] = make_int4((int)q[0], (int)q[1], (int)q[2], (int)q[3]);
}

// ---------------- pre-kernel 2: convert x fp32 -> bf16 [M][K] -------------
// thread = 8 floats (two float4 loads) -> one 16B store.
__global__ __launch_bounds__(256) void k_cvtA(const float* __restrict__ X,
                                              unsigned short* __restrict__ XB){
  int t = blockIdx.x * 256 + threadIdx.x;     // octet id; total M*KK/8
  const float4* src = reinterpret_cast<const float4*>(X) + (size_t)t * 2;
  float4 a = src[0], b = src[1];
  reinterpret_cast<int4*>(XB)[t] = make_int4(
      (int)pack2(a.x, a.y), (int)pack2(a.z, a.w),
      (int)pack2(b.x, b.y), (int)pack2(b.z, b.w));
}

// ---------------- fast GEMM: m97 structure, both operands bf16 K-major ----
// 128x128 tile, BK=32, dbuf LDS, global_load_lds width-16, 4 waves (2x2),
// each wave 64x64 = 4x4 frags of mfma_f32_16x16x32_bf16. XCD swizzle (T1).
__global__ __launch_bounds__(256) void k_gemm_fast(const unsigned short* __restrict__ A,
                                                   const unsigned short* __restrict__ B,
                                                   const float* __restrict__ Bias,
                                                   float* __restrict__ C){
  __shared__ unsigned short As[2][BM][BK];
  __shared__ unsigned short Bs[2][BN][BK];
  const int tid = threadIdx.x;
  // XCD-aware bijective swizzle: gridDim.x = 5504 is divisible by 8.
  const int cpx = gridDim.x >> 3;
  const int wg  = (blockIdx.x & 7) * cpx + (blockIdx.x >> 3);
  const int NT = NN / BN;                       // 86
  const int mt = wg / NT, nt = wg % NT;
  const unsigned short* Ab = A + (size_t)mt * BM * KK;
  const unsigned short* Bb = B + (size_t)nt * BN * KK;
  const int lane = tid & 63, wid = tid >> 6;
  const int wm = wid >> 1, wn = wid & 1;
  const int lr = lane & 15, lk = (lane >> 4) << 3;

  auto stage = [&](int buf, int kt){
    #pragma unroll
    for (int r = 0; r < 2; ++r){
      int c = r * 256 + tid, row = c >> 2, k0 = (c & 3) << 3;
      gload16(Ab + (size_t)row * KK + kt * BK + k0, &As[buf][row][k0]);
      gload16(Bb + (size_t)row * KK + kt * BK + k0, &Bs[buf][row][k0]);
    }
  };

  f32x4 acc[4][4] = {};
  stage(0, 0);
  __syncthreads();
  const int KT = KK / BK;                      // 128
  for (int kt = 0; kt < KT; ++kt){
    int cur = kt & 1;
    if (kt + 1 < KT) stage(cur ^ 1, kt + 1);   // async prefetch into other buf
    bf16x8 af[4], bfr[4];
    #pragma unroll
    for (int i = 0; i < 4; ++i)
      af[i] = *reinterpret_cast<const bf16x8*>(&As[cur][wm*64 + i*16 + lr][lk]);
    #pragma unroll
    for (int i = 0; i < 4; ++i)
      bfr[i] = *reinterpret_cast<const bf16x8*>(&Bs[cur][wn*64 + i*16 + lr][lk]);
    #pragma unroll
    for (int i = 0; i < 4; ++i)
      #pragma unroll
      for (int j = 0; j < 4; ++j)
        acc[i][j] = __builtin_amdgcn_mfma_f32_16x16x32_bf16(af[i], bfr[j], acc[i][j], 0, 0, 0);
    __syncthreads();                           // drains vmcnt+lgkm, guards dbuf swap
  }
  const int cm = mt * BM + wm * 64;
  const int cn = nt * BN + wn * 64;
  float bv[4];
  #pragma unroll
  for (int j = 0; j < 4; ++j) bv[j] = Bias[cn + j*16 + lr];
  #pragma unroll
  for (int i = 0; i < 4; ++i)
    #pragma unroll
    for (int j = 0; j < 4; ++j)
      #pragma unroll
      for (int r = 0; r < 4; ++r){
        size_t rr = (size_t)(cm + i*16 + (lane >> 4)*4 + r);
        C[rr * NN + (cn + j*16 + lr)] = acc[i][j][r] + bv[j];
      }
}

// ---------------- fallback (verified round 3): A fp32, reg-staged ---------
__global__ __launch_bounds__(256) void k_gemm_ws(const float* __restrict__ A,
                                                 const unsigned short* __restrict__ B,
                                                 const float* __restrict__ Bias,
                                                 float* __restrict__ C){
  __shared__ unsigned short As[2][BM][BK];
  __shared__ unsigned short Bs[2][BN][BK];
  const int tid = threadIdx.x;
  const int NT = NN / BN;
  const int mt = blockIdx.x / NT, nt = blockIdx.x % NT;
  const float*          Ab = A + (size_t)mt * BM * KK;
  const unsigned short* Bb = B + (size_t)nt * BN * KK;
  const int lane = tid & 63, wid = tid >> 6;
  const int wm = wid >> 1, wn = wid & 1;
  const int lr = lane & 15, lk = (lane >> 4) << 3;

  auto ld = [&](int kt, float4* ra, int4* rb){
    #pragma unroll
    for (int r = 0; r < 2; ++r){
      int c = r * 256 + tid, row = c >> 2, k0 = (c & 3) << 3;
      const float* src = Ab + (size_t)row * KK + kt * BK + k0;
      ra[2*r]   = *reinterpret_cast<const float4*>(src);
      ra[2*r+1] = *reinterpret_cast<const float4*>(src + 4);
      rb[r] = *reinterpret_cast<const int4*>(Bb + (size_t)row * KK + kt * BK + k0);
    }
  };
  auto st = [&](int buf, const float4* ra, const int4* rb){
    #pragma unroll
    for (int r = 0; r < 2; ++r){
      int c = r * 256 + tid, row = c >> 2, k0 = (c & 3) << 3;
      unsigned q[4];
      #pragma unroll
      for (int i = 0; i < 4; ++i)
        q[i] = pack2(ra[2*r + (i >> 1)][(i & 1) * 2], ra[2*r + (i >> 1)][(i & 1) * 2 + 1]);
      *reinterpret_cast<int4*>(&As[buf][row][k0]) =
          make_int4((int)q[0], (int)q[1], (int)q[2], (int)q[3]);
      *reinterpret_cast<int4*>(&Bs[buf][row][k0]) = rb[r];
    }
  };

  f32x4 acc[4][4] = {};
  {
    float4 ra[4]; int4 rb[2];
    ld(0, ra, rb);
    st(0, ra, rb);
  }
  __syncthreads();
  const int KT = KK / BK;
  for (int kt = 0; kt < KT; ++kt){
    int cur = kt & 1;
    float4 na[4]; int4 nb[2];
    if (kt + 1 < KT) ld(kt + 1, na, nb);
    bf16x8 af[4], bfr[4];
    #pragma unroll
    for (int i = 0; i < 4; ++i)
      af[i] = *reinterpret_cast<const bf16x8*>(&As[cur][wm*64 + i*16 + lr][lk]);
    #pragma unroll
    for (int i = 0; i < 4; ++i)
      bfr[i] = *reinterpret_cast<const bf16x8*>(&Bs[cur][wn*64 + i*16 + lr][lk]);
    #pragma unroll
    for (int i = 0; i < 4; ++i)
      #pragma unroll
      for (int j = 0; j < 4; ++j)
        acc[i][j] = __builtin_amdgcn_mfma_f32_16x16x32_bf16(af[i], bfr[j], acc[i][j], 0, 0, 0);
    if (kt + 1 < KT) st(cur ^ 1, na, nb);
    __syncthreads();
  }
  const int cm = mt * BM + wm * 64;
  const int cn = nt * BN + wn * 64;
  float bv[4];
  #pragma unroll
  for (int j = 0; j < 4; ++j) bv[j] = Bias[cn + j*16 + lr];
  #pragma unroll
  for (int i = 0; i < 4; ++i)
    #pragma unroll
    for (int j = 0; j < 4; ++j)
      #pragma unroll
      for (int r = 0; r < 4; ++r){
        size_t rr = (size_t)(cm + i*16 + (lane >> 4)*4 + r);
        C[rr * NN + (cn + j*16 + lr)] = acc[i][j][r] + bv[j];
      }
}

extern "C" void kernel_launch(void* const* d_in, const int* in_sizes, int n_in,
                              void* d_out, int out_size, void* d_ws, size_t ws_size,
                              hipStream_t stream){
  const float* x    = (const float*)d_in[0];   // fp32 [M][K] (fp16 ref -> float)
  const int*   w    = (const int*)d_in[1];     // [N][K/2] packed bytes
  const float* s    = (const float*)d_in[2];   // fp32 [N][NG]
  const float* bias = (const float*)d_in[3];   // fp32 [N]
  float* out = (float*)d_out;                  // fp32 [M][N]
  const int M = in_sizes[0] / KK;              // 8192
  const int grid = (M / BM) * (NN / BN);       // 64*86 = 5504
  const size_t needW = (size_t)NN * KK * 2;    // 90.2 MB for bf16 W
  const size_t needA = (size_t)M * KK * 2;     // 67.1 MB for bf16 x
  const int dq_blocks = (NN * (KK / 8)) / 256; // 22016

  if (ws_size >= needW + needA){
    unsigned short* wb = (unsigned short*)d_ws;
    unsigned short* xb = (unsigned short*)((char*)d_ws + needW);
    k_dequant<<<dq_blocks, 256, 0, stream>>>(w, s, wb);
    k_cvtA<<<(M * (KK / 8)) / 256, 256, 0, stream>>>(x, xb);
    k_gemm_fast<<<grid, 256, 0, stream>>>(xb, wb, bias, out);
  } else {
    unsigned short* wb = (unsigned short*)d_ws;   // ws >= needW observed (round 3)
    k_dequant<<<dq_blocks, 256, 0, stream>>>(w, s, wb);
    k_gemm_ws<<<grid, 256, 0, stream>>>(x, wb, bias, out);
  }
}

// Round 5
// 824.027 us; speedup vs baseline: 1.6454x; 1.3286x over previous
//
#include <hip/hip_runtime.h>

#define DEVINL __device__ __forceinline__

typedef __bf16 bf16x8 __attribute__((ext_vector_type(8)));
typedef float  f32x4  __attribute__((ext_vector_type(4)));

constexpr int KK = 4096;        // K
constexpr int NN = 11008;       // N
constexpr int NG = 32;          // K / group_size(128)

DEVINL unsigned short f2bf(float f){
  union { float f; unsigned u; } v; v.f = f;
  unsigned r = v.u + 0x7FFF + ((v.u >> 16) & 1);   // RNE; inputs finite here
  return (unsigned short)(r >> 16);
}
DEVINL unsigned pack2(float lo, float hi){
  return (unsigned)f2bf(lo) | ((unsigned)f2bf(hi) << 16);
}
DEVINL void gload16(const void* g, void* l){
  __builtin_amdgcn_global_load_lds(
      (const __attribute__((address_space(1))) void*)g,
      (__attribute__((address_space(3))) void*)l, 16, 0, 0);
}

// ---------------- pre-kernel 1: dequant W (int4-in-int32) -> bf16 [N][K] --
__global__ __launch_bounds__(256) void k_dequant(const int* __restrict__ W,
                                                 const float* __restrict__ S,
                                                 unsigned short* __restrict__ WB){
  int t = blockIdx.x * 256 + threadIdx.x;     // quad id; total NN*(KK/8)
  int row = t >> 9;                           // 512 quads per N-row
  int kp0 = (t & 511) << 2;
  int g   = kp0 >> 6;
  float s = S[row * NG + g];
  const int4 p = reinterpret_cast<const int4*>(W)[t];
  const int* pb = reinterpret_cast<const int*>(&p);
  unsigned q[4];
  #pragma unroll
  for (int i = 0; i < 4; ++i){
    int b = pb[i];
    float lo = ((float)(b & 15)        - 8.0f) * s;
    float hi = ((float)((b >> 4) & 15) - 8.0f) * s;
    q[i] = pack2(lo, hi);
  }
  reinterpret_cast<int4*>(WB)[t] = make_int4((int)q[0], (int)q[1], (int)q[2], (int)q[3]);
}

// ---------------- pre-kernel 2: convert x fp32 -> bf16 [M][K] -------------
__global__ __launch_bounds__(256) void k_cvtA(const float* __restrict__ X,
                                              unsigned short* __restrict__ XB){
  int t = blockIdx.x * 256 + threadIdx.x;
  const float4* src = reinterpret_cast<const float4*>(X) + (size_t)t * 2;
  float4 a = src[0], b = src[1];
  reinterpret_cast<int4*>(XB)[t] = make_int4(
      (int)pack2(a.x, a.y), (int)pack2(a.z, a.w),
      (int)pack2(b.x, b.y), (int)pack2(b.z, b.w));
}

// =================== 8-phase 256x256 GEMM (T1+T2+T3+T4+T5) ================
// 512 thr = 8 waves (2m x 4n). K-tile BK=64. LDS: 2 buf x {A0,A1,B0,B1} x
// 128x64 bf16 (16 KB each) = 128 KiB. XOR-swizzle (row&7)<<4 applied as
// inverse-swizzled GLOBAL source + swizzled ds_read; gload_lds dest linear.
constexpr int BM2 = 256, BN2 = 256, BK2 = 64;
constexpr int HBY = 16384;      // half-tile bytes
constexpr int BUFBY = 65536;    // one dbuf buffer (4 half-tiles)

#define WAIT4  asm volatile("s_waitcnt vmcnt(4)" ::: "memory")
#define NOWAIT ((void)0)

// Phase: ds-read frags -> stage one half-tile -> counted wait -> barrier ->
// setprio(1) 16xMFMA setprio(0) -> barrier.
#define PHASE(BUF, HA, HB, STAGE_STMT, WAIT_STMT)                              \
  do {                                                                         \
    bf16x8 af_[4][2], bf_[2][2];                                               \
    _Pragma("unroll") for (int i_ = 0; i_ < 4; ++i_)                           \
      _Pragma("unroll") for (int ks_ = 0; ks_ < 2; ++ks_)                      \
        af_[i_][ks_] = frag((BUF), (HA), wm*64 + i_*16 + lr, ks_*64 + hi*16);  \
    _Pragma("unroll") for (int j_ = 0; j_ < 2; ++j_)                           \
      _Pragma("unroll") for (int ks_ = 0; ks_ < 2; ++ks_)                      \
        bf_[j_][ks_] = frag((BUF), 2+(HB), wn*32 + j_*16 + lr, ks_*64 + hi*16);\
    STAGE_STMT;                                                                \
    WAIT_STMT;                                                                 \
    __builtin_amdgcn_s_barrier();                                              \
    asm volatile("" ::: "memory");                                             \
    __builtin_amdgcn_s_setprio(1);                                             \
    _Pragma("unroll") for (int i_ = 0; i_ < 4; ++i_)                           \
      _Pragma("unroll") for (int j_ = 0; j_ < 2; ++j_)                         \
        _Pragma("unroll") for (int ks_ = 0; ks_ < 2; ++ks_)                    \
          acc[(HA)*4 + i_][(HB)*2 + j_] = __builtin_amdgcn_mfma_f32_16x16x32_bf16( \
              af_[i_][ks_], bf_[j_][ks_], acc[(HA)*4 + i_][(HB)*2 + j_], 0, 0, 0); \
    __builtin_amdgcn_s_setprio(0);                                             \
    __builtin_amdgcn_s_barrier();                                              \
    asm volatile("" ::: "memory");                                             \
  } while (0)

__global__ __launch_bounds__(512, 2) void k_gemm8(const unsigned short* __restrict__ A,
                                                  const unsigned short* __restrict__ B,
                                                  const float* __restrict__ Bias,
                                                  float* __restrict__ C){
  __shared__ char smem[131072];
  const int tid = threadIdx.x, lane = tid & 63, wid = tid >> 6;
  const int wm = wid >> 2, wn = wid & 3;       // 2 x 4 waves
  const int lr = lane & 15, hi = lane >> 4;
  // XCD-aware swizzle: grid = 1376, divisible by 8.
  const int cpx = gridDim.x >> 3;
  const int wg  = (blockIdx.x & 7) * cpx + (blockIdx.x >> 3);
  const int NTT = NN / BN2;                    // 43
  const int mt = wg / NTT, nt = wg % NTT;
  const char* Ab = (const char*)(A + (size_t)mt * BM2 * KK);
  const char* Bb = (const char*)(B + (size_t)nt * BN2 * KK);
  const int srow  = tid >> 3;                  // staging row within half (0..63, x2)
  const int scolb = (tid & 7) * 16;            // staging col byte (0..112)

  // Stage one half-tile (sel: 0=A0,1=A1,2=B0,3=B1) of K-tile kt into buf.
  auto stage_half = [&](int buf, int sel, int kt){
    const char* base = ((sel >= 2) ? Bb : Ab) + (size_t)((sel & 1) * 128) * KK * 2;
    #pragma unroll
    for (int r = 0; r < 2; ++r){
      int row = r * 64 + srow;
      const char* src = base + (size_t)row * (KK * 2) + kt * (BK2 * 2)
                      + (scolb ^ ((row & 7) << 4));          // inverse-swizzled src
      char* dst = smem + buf * BUFBY + sel * HBY + r * 8192 + tid * 16;  // linear dst
      gload16(src, dst);
    }
  };
  // Swizzled LDS fragment read (16B), sel as above.
  auto frag = [&](int buf, int sel, int row, int bcol) -> bf16x8 {
    return *reinterpret_cast<const bf16x8*>(
        smem + buf * BUFBY + sel * HBY + row * 128 + (bcol ^ ((row & 7) << 4)));
  };

  f32x4 acc[8][4] = {};

  // Prologue: stage K-tile 0 (order A0,B0,B1,A1), wait first two halves.
  stage_half(0, 0, 0);
  stage_half(0, 2, 0);
  stage_half(0, 3, 0);
  stage_half(0, 1, 0);
  WAIT4;                                       // A0,B0 landed; B1,A1 in flight
  __builtin_amdgcn_s_barrier();
  asm volatile("" ::: "memory");

  const int NT = KK / BK2;                     // 64 K-tiles
  for (int t = 0; t < NT - 1; ++t){
    const int buf = t & 1;
    // Wait ledger (2 load-instr per half, own-wave):
    // p1 wait: outstanding {B1,A1}(t) + {A0'}(t+1) = 6 -> vmcnt(4): B1 lands (p2 needs it)
    // p2 wait: outstanding {A1}(t) + {A0',B0'} = 6    -> vmcnt(4): A1 lands (p3 needs it)
    // p4 wait: outstanding {A0',B0',B1',A1'} = 8      -> vmcnt(4): A0',B0' land (next p1)
    PHASE(buf, 0, 0, stage_half(buf ^ 1, 0, t + 1), WAIT4);
    PHASE(buf, 0, 1, stage_half(buf ^ 1, 2, t + 1), WAIT4);
    PHASE(buf, 1, 0, stage_half(buf ^ 1, 3, t + 1), NOWAIT);
    PHASE(buf, 1, 1, stage_half(buf ^ 1, 1, t + 1), WAIT4);
  }
  // Epilogue K-tile: drain once (legal outside main loop), then pure compute.
  asm volatile("s_waitcnt vmcnt(0)" ::: "memory");
  __builtin_amdgcn_s_barrier();
  asm volatile("" ::: "memory");
  {
    const int buf = (NT - 1) & 1;
    PHASE(buf, 0, 0, NOWAIT, NOWAIT);
    PHASE(buf, 0, 1, NOWAIT, NOWAIT);
    PHASE(buf, 1, 0, NOWAIT, NOWAIT);
    PHASE(buf, 1, 1, NOWAIT, NOWAIT);
  }

  // Epilogue: bias + fp32 store. acc[i][j]: row = (i>>2)*128 + wm*64 + (i&3)*16
  // + hi*4 + r ; col = (j>>1)*128 + wn*32 + (j&1)*16 + lr.
  const int cmb = mt * BM2, cnb = nt * BN2;
  #pragma unroll
  for (int j = 0; j < 4; ++j){
    int col = cnb + (j >> 1) * 128 + wn * 32 + (j & 1) * 16 + lr;
    float bv = Bias[col];
    #pragma unroll
    for (int i = 0; i < 8; ++i){
      int row0 = cmb + (i >> 2) * 128 + wm * 64 + (i & 3) * 16 + hi * 4;
      #pragma unroll
      for (int r = 0; r < 4; ++r)
        C[(size_t)(row0 + r) * NN + col] = acc[i][j][r] + bv;
    }
  }
}

// ---------------- fallback (verified round 4): 128x128 m97 structure ------
constexpr int BM = 128, BN = 128, BK = 32;
__global__ __launch_bounds__(256) void k_gemm_fast(const unsigned short* __restrict__ A,
                                                   const unsigned short* __restrict__ B,
                                                   const float* __restrict__ Bias,
                                                   float* __restrict__ C){
  __shared__ unsigned short As[2][BM][BK];
  __shared__ unsigned short Bs[2][BN][BK];
  const int tid = threadIdx.x;
  const int cpx = gridDim.x >> 3;
  const int wg  = (blockIdx.x & 7) * cpx + (blockIdx.x >> 3);
  const int NT = NN / BN;
  const int mt = wg / NT, nt = wg % NT;
  const unsigned short* Ab = A + (size_t)mt * BM * KK;
  const unsigned short* Bb = B + (size_t)nt * BN * KK;
  const int lane = tid & 63, wid = tid >> 6;
  const int wm = wid >> 1, wn = wid & 1;
  const int lr = lane & 15, lk = (lane >> 4) << 3;

  auto stage = [&](int buf, int kt){
    #pragma unroll
    for (int r = 0; r < 2; ++r){
      int c = r * 256 + tid, row = c >> 2, k0 = (c & 3) << 3;
      gload16(Ab + (size_t)row * KK + kt * BK + k0, &As[buf][row][k0]);
      gload16(Bb + (size_t)row * KK + kt * BK + k0, &Bs[buf][row][k0]);
    }
  };

  f32x4 acc[4][4] = {};
  stage(0, 0);
  __syncthreads();
  const int KT = KK / BK;
  for (int kt = 0; kt < KT; ++kt){
    int cur = kt & 1;
    if (kt + 1 < KT) stage(cur ^ 1, kt + 1);
    bf16x8 af[4], bfr[4];
    #pragma unroll
    for (int i = 0; i < 4; ++i)
      af[i] = *reinterpret_cast<const bf16x8*>(&As[cur][wm*64 + i*16 + lr][lk]);
    #pragma unroll
    for (int i = 0; i < 4; ++i)
      bfr[i] = *reinterpret_cast<const bf16x8*>(&Bs[cur][wn*64 + i*16 + lr][lk]);
    #pragma unroll
    for (int i = 0; i < 4; ++i)
      #pragma unroll
      for (int j = 0; j < 4; ++j)
        acc[i][j] = __builtin_amdgcn_mfma_f32_16x16x32_bf16(af[i], bfr[j], acc[i][j], 0, 0, 0);
    __syncthreads();
  }
  const int cm = mt * BM + wm * 64;
  const int cn = nt * BN + wn * 64;
  float bv[4];
  #pragma unroll
  for (int j = 0; j < 4; ++j) bv[j] = Bias[cn + j*16 + lr];
  #pragma unroll
  for (int i = 0; i < 4; ++i)
    #pragma unroll
    for (int j = 0; j < 4; ++j)
      #pragma unroll
      for (int r = 0; r < 4; ++r){
        size_t rr = (size_t)(cm + i*16 + (lane >> 4)*4 + r);
        C[rr * NN + (cn + j*16 + lr)] = acc[i][j][r] + bv[j];
      }
}

// ---------------- fallback (verified round 3): A fp32, reg-staged ---------
__global__ __launch_bounds__(256) void k_gemm_ws(const float* __restrict__ A,
                                                 const unsigned short* __restrict__ B,
                                                 const float* __restrict__ Bias,
                                                 float* __restrict__ C){
  __shared__ unsigned short As[2][BM][BK];
  __shared__ unsigned short Bs[2][BN][BK];
  const int tid = threadIdx.x;
  const int NT = NN / BN;
  const int mt = blockIdx.x / NT, nt = blockIdx.x % NT;
  const float*          Ab = A + (size_t)mt * BM * KK;
  const unsigned short* Bb = B + (size_t)nt * BN * KK;
  const int lane = tid & 63, wid = tid >> 6;
  const int wm = wid >> 1, wn = wid & 1;
  const int lr = lane & 15, lk = (lane >> 4) << 3;

  auto ld = [&](int kt, float4* ra, int4* rb){
    #pragma unroll
    for (int r = 0; r < 2; ++r){
      int c = r * 256 + tid, row = c >> 2, k0 = (c & 3) << 3;
      const float* src = Ab + (size_t)row * KK + kt * BK + k0;
      ra[2*r]   = *reinterpret_cast<const float4*>(src);
      ra[2*r+1] = *reinterpret_cast<const float4*>(src + 4);
      rb[r] = *reinterpret_cast<const int4*>(Bb + (size_t)row * KK + kt * BK + k0);
    }
  };
  auto st = [&](int buf, const float4* ra, const int4* rb){
    #pragma unroll
    for (int r = 0; r < 2; ++r){
      int c = r * 256 + tid, row = c >> 2, k0 = (c & 3) << 3;
      unsigned q[4];
      #pragma unroll
      for (int i = 0; i < 4; ++i)
        q[i] = pack2(ra[2*r + (i >> 1)][(i & 1) * 2], ra[2*r + (i >> 1)][(i & 1) * 2 + 1]);
      *reinterpret_cast<int4*>(&As[buf][row][k0]) =
          make_int4((int)q[0], (int)q[1], (int)q[2], (int)q[3]);
      *reinterpret_cast<int4*>(&Bs[buf][row][k0]) = rb[r];
    }
  };

  f32x4 acc[4][4] = {};
  {
    float4 ra[4]; int4 rb[2];
    ld(0, ra, rb);
    st(0, ra, rb);
  }
  __syncthreads();
  const int KT = KK / BK;
  for (int kt = 0; kt < KT; ++kt){
    int cur = kt & 1;
    float4 na[4]; int4 nb[2];
    if (kt + 1 < KT) ld(kt + 1, na, nb);
    bf16x8 af[4], bfr[4];
    #pragma unroll
    for (int i = 0; i < 4; ++i)
      af[i] = *reinterpret_cast<const bf16x8*>(&As[cur][wm*64 + i*16 + lr][lk]);
    #pragma unroll
    for (int i = 0; i < 4; ++i)
      bfr[i] = *reinterpret_cast<const bf16x8*>(&Bs[cur][wn*64 + i*16 + lr][lk]);
    #pragma unroll
    for (int i = 0; i < 4; ++i)
      #pragma unroll
      for (int j = 0; j < 4; ++j)
        acc[i][j] = __builtin_amdgcn_mfma_f32_16x16x32_bf16(af[i], bfr[j], acc[i][j], 0, 0, 0);
    if (kt + 1 < KT) st(cur ^ 1, na, nb);
    __syncthreads();
  }
  const int cm = mt * BM + wm * 64;
  const int cn = nt * BN + wn * 64;
  float bv[4];
  #pragma unroll
  for (int j = 0; j < 4; ++j) bv[j] = Bias[cn + j*16 + lr];
  #pragma unroll
  for (int i = 0; i < 4; ++i)
    #pragma unroll
    for (int j = 0; j < 4; ++j)
      #pragma unroll
      for (int r = 0; r < 4; ++r){
        size_t rr = (size_t)(cm + i*16 + (lane >> 4)*4 + r);
        C[rr * NN + (cn + j*16 + lr)] = acc[i][j][r] + bv[j];
      }
}

extern "C" void kernel_launch(void* const* d_in, const int* in_sizes, int n_in,
                              void* d_out, int out_size, void* d_ws, size_t ws_size,
                              hipStream_t stream){
  const float* x    = (const float*)d_in[0];   // fp32 [M][K] (fp16 ref -> float)
  const int*   w    = (const int*)d_in[1];     // [N][K/2] packed bytes
  const float* s    = (const float*)d_in[2];   // fp32 [N][NG]
  const float* bias = (const float*)d_in[3];   // fp32 [N]
  float* out = (float*)d_out;                  // fp32 [M][N]
  const int M = in_sizes[0] / KK;              // 8192
  const size_t needW = (size_t)NN * KK * 2;    // 90.2 MB for bf16 W
  const size_t needA = (size_t)M * KK * 2;     // 67.1 MB for bf16 x
  const int dq_blocks = (NN * (KK / 8)) / 256;

  if (ws_size >= needW + needA){
    unsigned short* wb = (unsigned short*)d_ws;
    unsigned short* xb = (unsigned short*)((char*)d_ws + needW);
    k_dequant<<<dq_blocks, 256, 0, stream>>>(w, s, wb);
    k_cvtA<<<(M * (KK / 8)) / 256, 256, 0, stream>>>(x, xb);
    if ((M % BM2) == 0){
      const int grid8 = (M / BM2) * (NN / BN2);     // 32*43 = 1376
      k_gemm8<<<grid8, 512, 0, stream>>>(xb, wb, bias, out);
    } else {
      const int grid = (M / BM) * (NN / BN);
      k_gemm_fast<<<grid, 256, 0, stream>>>(xb, wb, bias, out);
    }
  } else {
    unsigned short* wb = (unsigned short*)d_ws;
    k_dequant<<<dq_blocks, 256, 0, stream>>>(w, s, wb);
    const int grid = (M / BM) * (NN / BN);
    k_gemm_ws<<<grid, 256, 0, stream>>>(x, wb, bias, out);
  }
}

// Round 6
// 757.555 us; speedup vs baseline: 1.7898x; 1.0877x over previous
//
#include <hip/hip_runtime.h>

#define DEVINL __device__ __forceinline__

typedef __bf16 bf16x8 __attribute__((ext_vector_type(8)));
typedef float  f32x4  __attribute__((ext_vector_type(4)));

constexpr int KK = 4096;        // K
constexpr int NN = 11008;       // N
constexpr int NG = 32;          // K / group_size(128)

DEVINL unsigned short f2bf(float f){
  union { float f; unsigned u; } v; v.f = f;
  unsigned r = v.u + 0x7FFF + ((v.u >> 16) & 1);   // RNE; inputs finite here
  return (unsigned short)(r >> 16);
}
DEVINL unsigned pack2(float lo, float hi){
  return (unsigned)f2bf(lo) | ((unsigned)f2bf(hi) << 16);
}
DEVINL void gload16(const void* g, void* l){
  __builtin_amdgcn_global_load_lds(
      (const __attribute__((address_space(1))) void*)g,
      (__attribute__((address_space(3))) void*)l, 16, 0, 0);
}

// ---------------- pre-kernel 1: dequant W (int4-in-int32) -> bf16 [N][K] --
__global__ __launch_bounds__(256) void k_dequant(const int* __restrict__ W,
                                                 const float* __restrict__ S,
                                                 unsigned short* __restrict__ WB){
  int t = blockIdx.x * 256 + threadIdx.x;     // quad id; total NN*(KK/8)
  int row = t >> 9;                           // 512 quads per N-row
  int kp0 = (t & 511) << 2;
  int g   = kp0 >> 6;
  float s = S[row * NG + g];
  const int4 p = reinterpret_cast<const int4*>(W)[t];
  const int* pb = reinterpret_cast<const int*>(&p);
  unsigned q[4];
  #pragma unroll
  for (int i = 0; i < 4; ++i){
    int b = pb[i];
    float lo = ((float)(b & 15)        - 8.0f) * s;
    float hi = ((float)((b >> 4) & 15) - 8.0f) * s;
    q[i] = pack2(lo, hi);
  }
  reinterpret_cast<int4*>(WB)[t] = make_int4((int)q[0], (int)q[1], (int)q[2], (int)q[3]);
}

// ---------------- pre-kernel 2: convert x fp32 -> bf16 [M][K] -------------
__global__ __launch_bounds__(256) void k_cvtA(const float* __restrict__ X,
                                              unsigned short* __restrict__ XB){
  int t = blockIdx.x * 256 + threadIdx.x;
  const float4* src = reinterpret_cast<const float4*>(X) + (size_t)t * 2;
  float4 a = src[0], b = src[1];
  reinterpret_cast<int4*>(XB)[t] = make_int4(
      (int)pack2(a.x, a.y), (int)pack2(a.z, a.w),
      (int)pack2(b.x, b.y), (int)pack2(b.z, b.w));
}

// =================== 8-phase 256x256 GEMM (T1+T2+T3+T4+T5) ================
// 512 thr = 8 waves (2m x 4n). K-tile BK=64. LDS: 2 buf x {A0,A1,B0,B1} x
// 128x64 bf16 (16 KB each) = 128 KiB. XOR-swizzle (row&7)<<4 applied as
// inverse-swizzled GLOBAL source + swizzled ds_read; gload_lds dest linear.
// R6: fragment reuse — phase order (A0B0)(A0B1)(A1B1)(A1B0); 24 ds_read_b128
// per wave per K-tile instead of 48 (round-5 was LDS-read-throughput-bound).
constexpr int BM2 = 256, BN2 = 256, BK2 = 64;
constexpr int HBY = 16384;      // half-tile bytes
constexpr int BUFBY = 65536;    // one dbuf buffer (4 half-tiles)

#define WAIT4  asm volatile("s_waitcnt vmcnt(4)" ::: "memory")
#define WAIT0  asm volatile("s_waitcnt vmcnt(0)" ::: "memory")
#define BAR()  do { __builtin_amdgcn_s_barrier(); asm volatile("" ::: "memory"); } while (0)

__global__ __launch_bounds__(512, 2) void k_gemm8(const unsigned short* __restrict__ A,
                                                  const unsigned short* __restrict__ B,
                                                  const float* __restrict__ Bias,
                                                  float* __restrict__ C){
  __shared__ char smem[131072];
  const int tid = threadIdx.x, lane = tid & 63, wid = tid >> 6;
  const int wm = wid >> 2, wn = wid & 3;       // 2 x 4 waves
  const int lr = lane & 15, hi = lane >> 4;
  // XCD-aware swizzle: grid = 1376, divisible by 8.
  const int cpx = gridDim.x >> 3;
  const int wg  = (blockIdx.x & 7) * cpx + (blockIdx.x >> 3);
  const int NTT = NN / BN2;                    // 43
  const int mt = wg / NTT, nt = wg % NTT;
  const char* Ab = (const char*)(A + (size_t)mt * BM2 * KK);
  const char* Bb = (const char*)(B + (size_t)nt * BN2 * KK);
  const int srow  = tid >> 3;                  // staging row within half (0..63, x2)
  const int scolb = (tid & 7) * 16;            // staging col byte (0..112)

  // Stage one half-tile (sel: 0=A0,1=A1,2=B0,3=B1) of K-tile kt into buf.
  auto stage_half = [&](int buf, int sel, int kt){
    const char* base = ((sel >= 2) ? Bb : Ab) + (size_t)((sel & 1) * 128) * KK * 2;
    #pragma unroll
    for (int r = 0; r < 2; ++r){
      int row = r * 64 + srow;
      const char* src = base + (size_t)row * (KK * 2) + kt * (BK2 * 2)
                      + (scolb ^ ((row & 7) << 4));          // inverse-swizzled src
      char* dst = smem + buf * BUFBY + sel * HBY + r * 8192 + tid * 16;  // linear dst
      gload16(src, dst);
    }
  };
  // Swizzled LDS fragment read (16B), sel as above.
  auto frag = [&](int buf, int sel, int row, int bcol) -> bf16x8 {
    return *reinterpret_cast<const bf16x8*>(
        smem + buf * BUFBY + sel * HBY + row * 128 + (bcol ^ ((row & 7) << 4)));
  };

  f32x4 acc[8][4] = {};
  bf16x8 af[4][2], bf0[2][2], bf1[2][2];

  auto read_A = [&](int buf, int ha){
    #pragma unroll
    for (int i = 0; i < 4; ++i)
      #pragma unroll
      for (int ks = 0; ks < 2; ++ks)
        af[i][ks] = frag(buf, ha, wm*64 + i*16 + lr, ks*64 + hi*16);
  };
  auto read_B = [&](int buf, int hb, bf16x8 (&bf)[2][2]){
    #pragma unroll
    for (int j = 0; j < 2; ++j)
      #pragma unroll
      for (int ks = 0; ks < 2; ++ks)
        bf[j][ks] = frag(buf, 2 + hb, wn*32 + j*16 + lr, ks*64 + hi*16);
  };
  auto mfma16 = [&](const bf16x8 (&bf)[2][2], int HA, int HB){
    __builtin_amdgcn_s_setprio(1);
    #pragma unroll
    for (int i = 0; i < 4; ++i)
      #pragma unroll
      for (int j = 0; j < 2; ++j)
        #pragma unroll
        for (int ks = 0; ks < 2; ++ks)
          acc[HA*4 + i][HB*2 + j] = __builtin_amdgcn_mfma_f32_16x16x32_bf16(
              af[i][ks], bf[j][ks], acc[HA*4 + i][HB*2 + j], 0, 0, 0);
    __builtin_amdgcn_s_setprio(0);
  };

  // Prologue: stage K-tile 0 (order A0,B0,B1,A1), wait first two halves.
  stage_half(0, 0, 0);
  stage_half(0, 2, 0);
  stage_half(0, 3, 0);
  stage_half(0, 1, 0);
  WAIT4;                                       // A0,B0 landed; B1,A1 in flight
  BAR();

  const int NT = KK / BK2;                     // 64 K-tiles
  for (int t = 0; t < NT - 1; ++t){
    const int buf = t & 1;
    // Wait ledger (2 load-instr per half, own-wave) — unchanged from round 5:
    // p1 wait: out {B1,A1}(t)+{A0'} = 6 -> vmcnt(4): B1(t) lands (p2 reads it)
    // p2 wait: out {A1}(t)+{A0',B0'} = 6 -> vmcnt(4): A1(t) lands (p3 reads it)
    // p4 wait: out {A0',B0',B1',A1'} = 8 -> vmcnt(4): A0',B0' land (next p1)
    // p1: (A0,B0) — read A0 + B0
    read_A(buf, 0); read_B(buf, 0, bf0);
    stage_half(buf ^ 1, 0, t + 1); WAIT4; BAR();
    mfma16(bf0, 0, 0); BAR();
    // p2: (A0,B1) — A0 held, read B1
    read_B(buf, 1, bf1);
    stage_half(buf ^ 1, 2, t + 1); WAIT4; BAR();
    mfma16(bf1, 0, 1); BAR();
    // p3: (A1,B1) — B1 held, read A1 (overwrites af)
    read_A(buf, 1);
    stage_half(buf ^ 1, 3, t + 1); BAR();
    mfma16(bf1, 1, 1); BAR();
    // p4: (A1,B0) — both held, no reads
    stage_half(buf ^ 1, 1, t + 1); WAIT4; BAR();
    mfma16(bf0, 1, 0); BAR();
  }
  // Epilogue K-tile: drain once (legal outside main loop), then pure compute.
  WAIT0;
  BAR();
  {
    const int buf = (NT - 1) & 1;
    read_A(buf, 0); read_B(buf, 0, bf0);
    mfma16(bf0, 0, 0);
    read_B(buf, 1, bf1);
    mfma16(bf1, 0, 1);
    read_A(buf, 1);
    mfma16(bf1, 1, 1);
    mfma16(bf0, 1, 0);
  }

  // Epilogue: bias + fp32 store. acc[i][j]: row = (i>>2)*128 + wm*64 + (i&3)*16
  // + hi*4 + r ; col = (j>>1)*128 + wn*32 + (j&1)*16 + lr.
  const int cmb = mt * BM2, cnb = nt * BN2;
  #pragma unroll
  for (int j = 0; j < 4; ++j){
    int col = cnb + (j >> 1) * 128 + wn * 32 + (j & 1) * 16 + lr;
    float bv = Bias[col];
    #pragma unroll
    for (int i = 0; i < 8; ++i){
      int row0 = cmb + (i >> 2) * 128 + wm * 64 + (i & 3) * 16 + hi * 4;
      #pragma unroll
      for (int r = 0; r < 4; ++r)
        C[(size_t)(row0 + r) * NN + col] = acc[i][j][r] + bv;
    }
  }
}

// ---------------- fallback (verified round 4): 128x128 m97 structure ------
constexpr int BM = 128, BN = 128, BK = 32;
__global__ __launch_bounds__(256) void k_gemm_fast(const unsigned short* __restrict__ A,
                                                   const unsigned short* __restrict__ B,
                                                   const float* __restrict__ Bias,
                                                   float* __restrict__ C){
  __shared__ unsigned short As[2][BM][BK];
  __shared__ unsigned short Bs[2][BN][BK];
  const int tid = threadIdx.x;
  const int cpx = gridDim.x >> 3;
  const int wg  = (blockIdx.x & 7) * cpx + (blockIdx.x >> 3);
  const int NT = NN / BN;
  const int mt = wg / NT, nt = wg % NT;
  const unsigned short* Ab = A + (size_t)mt * BM * KK;
  const unsigned short* Bb = B + (size_t)nt * BN * KK;
  const int lane = tid & 63, wid = tid >> 6;
  const int wm = wid >> 1, wn = wid & 1;
  const int lr = lane & 15, lk = (lane >> 4) << 3;

  auto stage = [&](int buf, int kt){
    #pragma unroll
    for (int r = 0; r < 2; ++r){
      int c = r * 256 + tid, row = c >> 2, k0 = (c & 3) << 3;
      gload16(Ab + (size_t)row * KK + kt * BK + k0, &As[buf][row][k0]);
      gload16(Bb + (size_t)row * KK + kt * BK + k0, &Bs[buf][row][k0]);
    }
  };

  f32x4 acc[4][4] = {};
  stage(0, 0);
  __syncthreads();
  const int KT = KK / BK;
  for (int kt = 0; kt < KT; ++kt){
    int cur = kt & 1;
    if (kt + 1 < KT) stage(cur ^ 1, kt + 1);
    bf16x8 af[4], bfr[4];
    #pragma unroll
    for (int i = 0; i < 4; ++i)
      af[i] = *reinterpret_cast<const bf16x8*>(&As[cur][wm*64 + i*16 + lr][lk]);
    #pragma unroll
    for (int i = 0; i < 4; ++i)
      bfr[i] = *reinterpret_cast<const bf16x8*>(&Bs[cur][wn*64 + i*16 + lr][lk]);
    #pragma unroll
    for (int i = 0; i < 4; ++i)
      #pragma unroll
      for (int j = 0; j < 4; ++j)
        acc[i][j] = __builtin_amdgcn_mfma_f32_16x16x32_bf16(af[i], bfr[j], acc[i][j], 0, 0, 0);
    __syncthreads();
  }
  const int cm = mt * BM + wm * 64;
  const int cn = nt * BN + wn * 64;
  float bv[4];
  #pragma unroll
  for (int j = 0; j < 4; ++j) bv[j] = Bias[cn + j*16 + lr];
  #pragma unroll
  for (int i = 0; i < 4; ++i)
    #pragma unroll
    for (int j = 0; j < 4; ++j)
      #pragma unroll
      for (int r = 0; r < 4; ++r){
        size_t rr = (size_t)(cm + i*16 + (lane >> 4)*4 + r);
        C[rr * NN + (cn + j*16 + lr)] = acc[i][j][r] + bv[j];
      }
}

// ---------------- fallback (verified round 3): A fp32, reg-staged ---------
__global__ __launch_bounds__(256) void k_gemm_ws(const float* __restrict__ A,
                                                 const unsigned short* __restrict__ B,
                                                 const float* __restrict__ Bias,
                                                 float* __restrict__ C){
  __shared__ unsigned short As[2][BM][BK];
  __shared__ unsigned short Bs[2][BN][BK];
  const int tid = threadIdx.x;
  const int NT = NN / BN;
  const int mt = blockIdx.x / NT, nt = blockIdx.x % NT;
  const float*          Ab = A + (size_t)mt * BM * KK;
  const unsigned short* Bb = B + (size_t)nt * BN * KK;
  const int lane = tid & 63, wid = tid >> 6;
  const int wm = wid >> 1, wn = wid & 1;
  const int lr = lane & 15, lk = (lane >> 4) << 3;

  auto ld = [&](int kt, float4* ra, int4* rb){
    #pragma unroll
    for (int r = 0; r < 2; ++r){
      int c = r * 256 + tid, row = c >> 2, k0 = (c & 3) << 3;
      const float* src = Ab + (size_t)row * KK + kt * BK + k0;
      ra[2*r]   = *reinterpret_cast<const float4*>(src);
      ra[2*r+1] = *reinterpret_cast<const float4*>(src + 4);
      rb[r] = *reinterpret_cast<const int4*>(Bb + (size_t)row * KK + kt * BK + k0);
    }
  };
  auto st = [&](int buf, const float4* ra, const int4* rb){
    #pragma unroll
    for (int r = 0; r < 2; ++r){
      int c = r * 256 + tid, row = c >> 2, k0 = (c & 3) << 3;
      unsigned q[4];
      #pragma unroll
      for (int i = 0; i < 4; ++i)
        q[i] = pack2(ra[2*r + (i >> 1)][(i & 1) * 2], ra[2*r + (i >> 1)][(i & 1) * 2 + 1]);
      *reinterpret_cast<int4*>(&As[buf][row][k0]) =
          make_int4((int)q[0], (int)q[1], (int)q[2], (int)q[3]);
      *reinterpret_cast<int4*>(&Bs[buf][row][k0]) = rb[r];
    }
  };

  f32x4 acc[4][4] = {};
  {
    float4 ra[4]; int4 rb[2];
    ld(0, ra, rb);
    st(0, ra, rb);
  }
  __syncthreads();
  const int KT = KK / BK;
  for (int kt = 0; kt < KT; ++kt){
    int cur = kt & 1;
    float4 na[4]; int4 nb[2];
    if (kt + 1 < KT) ld(kt + 1, na, nb);
    bf16x8 af[4], bfr[4];
    #pragma unroll
    for (int i = 0; i < 4; ++i)
      af[i] = *reinterpret_cast<const bf16x8*>(&As[cur][wm*64 + i*16 + lr][lk]);
    #pragma unroll
    for (int i = 0; i < 4; ++i)
      bfr[i] = *reinterpret_cast<const bf16x8*>(&Bs[cur][wn*64 + i*16 + lr][lk]);
    #pragma unroll
    for (int i = 0; i < 4; ++i)
      #pragma unroll
      for (int j = 0; j < 4; ++j)
        acc[i][j] = __builtin_amdgcn_mfma_f32_16x16x32_bf16(af[i], bfr[j], acc[i][j], 0, 0, 0);
    if (kt + 1 < KT) st(cur ^ 1, na, nb);
    __syncthreads();
  }
  const int cm = mt * BM + wm * 64;
  const int cn = nt * BN + wn * 64;
  float bv[4];
  #pragma unroll
  for (int j = 0; j < 4; ++j) bv[j] = Bias[cn + j*16 + lr];
  #pragma unroll
  for (int i = 0; i < 4; ++i)
    #pragma unroll
    for (int j = 0; j < 4; ++j)
      #pragma unroll
      for (int r = 0; r < 4; ++r){
        size_t rr = (size_t)(cm + i*16 + (lane >> 4)*4 + r);
        C[rr * NN + (cn + j*16 + lr)] = acc[i][j][r] + bv[j];
      }
}

extern "C" void kernel_launch(void* const* d_in, const int* in_sizes, int n_in,
                              void* d_out, int out_size, void* d_ws, size_t ws_size,
                              hipStream_t stream){
  const float* x    = (const float*)d_in[0];   // fp32 [M][K] (fp16 ref -> float)
  const int*   w    = (const int*)d_in[1];     // [N][K/2] packed bytes
  const float* s    = (const float*)d_in[2];   // fp32 [N][NG]
  const float* bias = (const float*)d_in[3];   // fp32 [N]
  float* out = (float*)d_out;                  // fp32 [M][N]
  const int M = in_sizes[0] / KK;              // 8192
  const size_t needW = (size_t)NN * KK * 2;    // 90.2 MB for bf16 W
  const size_t needA = (size_t)M * KK * 2;     // 67.1 MB for bf16 x
  const int dq_blocks = (NN * (KK / 8)) / 256;

  if (ws_size >= needW + needA){
    unsigned short* wb = (unsigned short*)d_ws;
    unsigned short* xb = (unsigned short*)((char*)d_ws + needW);
    k_dequant<<<dq_blocks, 256, 0, stream>>>(w, s, wb);
    k_cvtA<<<(M * (KK / 8)) / 256, 256, 0, stream>>>(x, xb);
    if ((M % BM2) == 0){
      const int grid8 = (M / BM2) * (NN / BN2);     // 32*43 = 1376
      k_gemm8<<<grid8, 512, 0, stream>>>(xb, wb, bias, out);
    } else {
      const int grid = (M / BM) * (NN / BN);
      k_gemm_fast<<<grid, 256, 0, stream>>>(xb, wb, bias, out);
    }
  } else {
    unsigned short* wb = (unsigned short*)d_ws;
    k_dequant<<<dq_blocks, 256, 0, stream>>>(w, s, wb);
    const int grid = (M / BM) * (NN / BN);
    k_gemm_ws<<<grid, 256, 0, stream>>>(x, wb, bias, out);
  }
}

// Round 8
// 732.491 us; speedup vs baseline: 1.8510x; 1.0342x over previous
//
#include <hip/hip_runtime.h>

#define DEVINL __device__ __forceinline__

typedef __bf16 bf16x8 __attribute__((ext_vector_type(8)));
typedef float  f32x4  __attribute__((ext_vector_type(4)));

constexpr int KK = 4096;        // K
constexpr int NN = 11008;       // N
constexpr int NG = 32;          // K / group_size(128)

DEVINL unsigned short f2bf(float f){
  union { float f; unsigned u; } v; v.f = f;
  unsigned r = v.u + 0x7FFF + ((v.u >> 16) & 1);   // RNE; inputs finite here
  return (unsigned short)(r >> 16);
}
DEVINL unsigned pack2(float lo, float hi){
  return (unsigned)f2bf(lo) | ((unsigned)f2bf(hi) << 16);
}
DEVINL void gload16(const void* g, void* l){
  __builtin_amdgcn_global_load_lds(
      (const __attribute__((address_space(1))) void*)g,
      (__attribute__((address_space(3))) void*)l, 16, 0, 0);
}

// ---------------- pre-kernel 1: dequant W (int4-in-int32) -> bf16 [N][K] --
__global__ __launch_bounds__(256) void k_dequant(const int* __restrict__ W,
                                                 const float* __restrict__ S,
                                                 unsigned short* __restrict__ WB){
  int t = blockIdx.x * 256 + threadIdx.x;     // quad id; total NN*(KK/8)
  int row = t >> 9;                           // 512 quads per N-row
  int kp0 = (t & 511) << 2;
  int g   = kp0 >> 6;
  float s = S[row * NG + g];
  const int4 p = reinterpret_cast<const int4*>(W)[t];
  const int* pb = reinterpret_cast<const int*>(&p);
  unsigned q[4];
  #pragma unroll
  for (int i = 0; i < 4; ++i){
    int b = pb[i];
    float lo = ((float)(b & 15)        - 8.0f) * s;
    float hi = ((float)((b >> 4) & 15) - 8.0f) * s;
    q[i] = pack2(lo, hi);
  }
  reinterpret_cast<int4*>(WB)[t] = make_int4((int)q[0], (int)q[1], (int)q[2], (int)q[3]);
}

// ---------------- pre-kernel 2: convert x fp32 -> bf16 [M][K] -------------
__global__ __launch_bounds__(256) void k_cvtA(const float* __restrict__ X,
                                              unsigned short* __restrict__ XB){
  int t = blockIdx.x * 256 + threadIdx.x;
  const float4* src = reinterpret_cast<const float4*>(X) + (size_t)t * 2;
  float4 a = src[0], b = src[1];
  reinterpret_cast<int4*>(XB)[t] = make_int4(
      (int)pack2(a.x, a.y), (int)pack2(a.z, a.w),
      (int)pack2(b.x, b.y), (int)pack2(b.z, b.w));
}

// =================== 256x256 GEMM, 2-barrier/K-tile (T1+T2+T4+T5) =========
// 512 thr = 8 waves (2m x 4n). K-tile BK=64. LDS: 2 buf x {A0,A1,B0,B1} x
// 128x64 bf16 (16 KB each) = 128 KiB. XOR-swizzle (row&7)<<4 via inverse-
// swizzled GLOBAL source + swizzled ds_read; gload_lds dest linear.
// R8: 2 barriers/K-tile. R7's 1-barrier raced: vmcnt is PER-WAVE, so a
// wait alone doesn't cover OTHER waves' staged portions — every dependent
// ds_read needs WAIT -> BARRIER before it. Counted vmcnt(4), never 0 mid-loop.
constexpr int BM2 = 256, BN2 = 256, BK2 = 64;
constexpr int HBY = 16384;      // half-tile bytes
constexpr int BUFBY = 65536;    // one dbuf buffer (4 half-tiles)

#define WAIT4  asm volatile("s_waitcnt vmcnt(4)" ::: "memory")
#define WAIT0  asm volatile("s_waitcnt vmcnt(0)" ::: "memory")
#define BAR()  do { __builtin_amdgcn_s_barrier(); asm volatile("" ::: "memory"); } while (0)

__global__ __launch_bounds__(512, 2) void k_gemm8(const unsigned short* __restrict__ A,
                                                  const unsigned short* __restrict__ B,
                                                  const float* __restrict__ Bias,
                                                  float* __restrict__ C){
  __shared__ char smem[131072];
  const int tid = threadIdx.x, lane = tid & 63, wid = tid >> 6;
  const int wm = wid >> 2, wn = wid & 3;       // 2 x 4 waves
  const int lr = lane & 15, hi = lane >> 4;
  // XCD-aware swizzle: grid = 1376, divisible by 8.
  const int cpx = gridDim.x >> 3;
  const int wg  = (blockIdx.x & 7) * cpx + (blockIdx.x >> 3);
  const int NTT = NN / BN2;                    // 43
  const int mt = wg / NTT, nt = wg % NTT;
  const char* Ab = (const char*)(A + (size_t)mt * BM2 * KK);
  const char* Bb = (const char*)(B + (size_t)nt * BN2 * KK);
  const int srow  = tid >> 3;                  // staging row within half (0..63, x2)
  const int scolb = (tid & 7) * 16;            // staging col byte (0..112)

  // Stage one half-tile (sel: 0=A0,1=A1,2=B0,3=B1) of K-tile kt into buf.
  auto stage_half = [&](int buf, int sel, int kt){
    const char* base = ((sel >= 2) ? Bb : Ab) + (size_t)((sel & 1) * 128) * KK * 2;
    #pragma unroll
    for (int r = 0; r < 2; ++r){
      int row = r * 64 + srow;
      const char* src = base + (size_t)row * (KK * 2) + kt * (BK2 * 2)
                      + (scolb ^ ((row & 7) << 4));          // inverse-swizzled src
      char* dst = smem + buf * BUFBY + sel * HBY + r * 8192 + tid * 16;  // linear dst
      gload16(src, dst);
    }
  };
  // Swizzled LDS fragment read (16B), sel as above.
  auto frag = [&](int buf, int sel, int row, int bcol) -> bf16x8 {
    return *reinterpret_cast<const bf16x8*>(
        smem + buf * BUFBY + sel * HBY + row * 128 + (bcol ^ ((row & 7) << 4)));
  };

  f32x4 acc[8][4] = {};
  bf16x8 af[4][2], bf0[2][2], bf1[2][2];

  auto read_A = [&](int buf, int ha){
    #pragma unroll
    for (int i = 0; i < 4; ++i)
      #pragma unroll
      for (int ks = 0; ks < 2; ++ks)
        af[i][ks] = frag(buf, ha, wm*64 + i*16 + lr, ks*64 + hi*16);
  };
  auto read_B = [&](int buf, int hb, bf16x8 (&bf)[2][2]){
    #pragma unroll
    for (int j = 0; j < 2; ++j)
      #pragma unroll
      for (int ks = 0; ks < 2; ++ks)
        bf[j][ks] = frag(buf, 2 + hb, wn*32 + j*16 + lr, ks*64 + hi*16);
  };
  auto mfma16 = [&](const bf16x8 (&bf)[2][2], int HA, int HB){
    __builtin_amdgcn_s_setprio(1);
    #pragma unroll
    for (int i = 0; i < 4; ++i)
      #pragma unroll
      for (int j = 0; j < 2; ++j)
        #pragma unroll
        for (int ks = 0; ks < 2; ++ks)
          acc[HA*4 + i][HB*2 + j] = __builtin_amdgcn_mfma_f32_16x16x32_bf16(
              af[i][ks], bf[j][ks], acc[HA*4 + i][HB*2 + j], 0, 0, 0);
    __builtin_amdgcn_s_setprio(0);
  };

  // Prologue: stage K-tile 0 (order A0,B0,B1,A1). WAIT4 -> own A0,B0 landed;
  // BAR -> ALL waves' A0,B0 landed. Entry invariant: out = {B1,A1} = 4.
  stage_half(0, 0, 0);
  stage_half(0, 2, 0);
  stage_half(0, 3, 0);
  stage_half(0, 1, 0);
  WAIT4;
  BAR();

  const int NT = KK / BK2;                     // 64 K-tiles
  // Per-tile ledger (own-wave gload instrs, 2 per half; vmcnt is FIFO):
  //  entry: out {B1,A1}(t)=4; A0,B0(t) landed globally (prev WAIT4+BAR).
  //  +stage A0',B0' -> 8; WAIT4 -> B1,A1(t) land (own); BAR#1 -> global.
  //  +stage B1',A1' -> 8; WAIT4 -> A0',B0' land (own); BAR#2 -> global,
  //  and all waves' ds_reads of buf are done (MFMAs consumed them) -> safe
  //  to overwrite buf in tile t+1. Exit out = {B1',A1'} = 4 = invariant.
  for (int t = 0; t < NT; ++t){
    const int buf = t & 1;
    const bool pf = (t + 1 < NT);
    read_A(buf, 0);                            // 8 ds_read_b128 (data landed)
    read_B(buf, 0, bf0);                       // 4
    if (pf){ stage_half(buf ^ 1, 0, t + 1); stage_half(buf ^ 1, 2, t + 1); }
    if (pf) WAIT4; else WAIT0;                 // own B1,A1(t) landed
    BAR();                                     // #1: ALL waves' B1,A1(t) landed
    read_B(buf, 1, bf1);                       // 4
    mfma16(bf0, 0, 0);
    mfma16(bf1, 0, 1);
    read_A(buf, 1);                            // 8 (new af regs; WAR via SSA)
    if (pf){ stage_half(buf ^ 1, 3, t + 1); stage_half(buf ^ 1, 1, t + 1); }
    mfma16(bf1, 1, 1);
    mfma16(bf0, 1, 0);
    if (pf) WAIT4;                             // own A0',B0'(t+1) landed
    BAR();                                     // #2: global; reads of buf done
  }

  // Epilogue: bias + fp32 store. acc[i][j]: row = (i>>2)*128 + wm*64 + (i&3)*16
  // + hi*4 + r ; col = (j>>1)*128 + wn*32 + (j&1)*16 + lr.
  const int cmb = mt * BM2, cnb = nt * BN2;
  #pragma unroll
  for (int j = 0; j < 4; ++j){
    int col = cnb + (j >> 1) * 128 + wn * 32 + (j & 1) * 16 + lr;
    float bv = Bias[col];
    #pragma unroll
    for (int i = 0; i < 8; ++i){
      int row0 = cmb + (i >> 2) * 128 + wm * 64 + (i & 3) * 16 + hi * 4;
      #pragma unroll
      for (int r = 0; r < 4; ++r)
        C[(size_t)(row0 + r) * NN + col] = acc[i][j][r] + bv;
    }
  }
}

// ---------------- fallback (verified round 4): 128x128 m97 structure ------
constexpr int BM = 128, BN = 128, BK = 32;
__global__ __launch_bounds__(256) void k_gemm_fast(const unsigned short* __restrict__ A,
                                                   const unsigned short* __restrict__ B,
                                                   const float* __restrict__ Bias,
                                                   float* __restrict__ C){
  __shared__ unsigned short As[2][BM][BK];
  __shared__ unsigned short Bs[2][BN][BK];
  const int tid = threadIdx.x;
  const int cpx = gridDim.x >> 3;
  const int wg  = (blockIdx.x & 7) * cpx + (blockIdx.x >> 3);
  const int NT = NN / BN;
  const int mt = wg / NT, nt = wg % NT;
  const unsigned short* Ab = A + (size_t)mt * BM * KK;
  const unsigned short* Bb = B + (size_t)nt * BN * KK;
  const int lane = tid & 63, wid = tid >> 6;
  const int wm = wid >> 1, wn = wid & 1;
  const int lr = lane & 15, lk = (lane >> 4) << 3;

  auto stage = [&](int buf, int kt){
    #pragma unroll
    for (int r = 0; r < 2; ++r){
      int c = r * 256 + tid, row = c >> 2, k0 = (c & 3) << 3;
      gload16(Ab + (size_t)row * KK + kt * BK + k0, &As[buf][row][k0]);
      gload16(Bb + (size_t)row * KK + kt * BK + k0, &Bs[buf][row][k0]);
    }
  };

  f32x4 acc[4][4] = {};
  stage(0, 0);
  __syncthreads();
  const int KT = KK / BK;
  for (int kt = 0; kt < KT; ++kt){
    int cur = kt & 1;
    if (kt + 1 < KT) stage(cur ^ 1, kt + 1);
    bf16x8 af[4], bfr[4];
    #pragma unroll
    for (int i = 0; i < 4; ++i)
      af[i] = *reinterpret_cast<const bf16x8*>(&As[cur][wm*64 + i*16 + lr][lk]);
    #pragma unroll
    for (int i = 0; i < 4; ++i)
      bfr[i] = *reinterpret_cast<const bf16x8*>(&Bs[cur][wn*64 + i*16 + lr][lk]);
    #pragma unroll
    for (int i = 0; i < 4; ++i)
      #pragma unroll
      for (int j = 0; j < 4; ++j)
        acc[i][j] = __builtin_amdgcn_mfma_f32_16x16x32_bf16(af[i], bfr[j], acc[i][j], 0, 0, 0);
    __syncthreads();
  }
  const int cm = mt * BM + wm * 64;
  const int cn = nt * BN + wn * 64;
  float bv[4];
  #pragma unroll
  for (int j = 0; j < 4; ++j) bv[j] = Bias[cn + j*16 + lr];
  #pragma unroll
  for (int i = 0; i < 4; ++i)
    #pragma unroll
    for (int j = 0; j < 4; ++j)
      #pragma unroll
      for (int r = 0; r < 4; ++r){
        size_t rr = (size_t)(cm + i*16 + (lane >> 4)*4 + r);
        C[rr * NN + (cn + j*16 + lr)] = acc[i][j][r] + bv[j];
      }
}

// ---------------- fallback (verified round 3): A fp32, reg-staged ---------
__global__ __launch_bounds__(256) void k_gemm_ws(const float* __restrict__ A,
                                                 const unsigned short* __restrict__ B,
                                                 const float* __restrict__ Bias,
                                                 float* __restrict__ C){
  __shared__ unsigned short As[2][BM][BK];
  __shared__ unsigned short Bs[2][BN][BK];
  const int tid = threadIdx.x;
  const int NT = NN / BN;
  const int mt = blockIdx.x / NT, nt = blockIdx.x % NT;
  const float*          Ab = A + (size_t)mt * BM * KK;
  const unsigned short* Bb = B + (size_t)nt * BN * KK;
  const int lane = tid & 63, wid = tid >> 6;
  const int wm = wid >> 1, wn = wid & 1;
  const int lr = lane & 15, lk = (lane >> 4) << 3;

  auto ld = [&](int kt, float4* ra, int4* rb){
    #pragma unroll
    for (int r = 0; r < 2; ++r){
      int c = r * 256 + tid, row = c >> 2, k0 = (c & 3) << 3;
      const float* src = Ab + (size_t)row * KK + kt * BK + k0;
      ra[2*r]   = *reinterpret_cast<const float4*>(src);
      ra[2*r+1] = *reinterpret_cast<const float4*>(src + 4);
      rb[r] = *reinterpret_cast<const int4*>(Bb + (size_t)row * KK + kt * BK + k0);
    }
  };
  auto st = [&](int buf, const float4* ra, const int4* rb){
    #pragma unroll
    for (int r = 0; r < 2; ++r){
      int c = r * 256 + tid, row = c >> 2, k0 = (c & 3) << 3;
      unsigned q[4];
      #pragma unroll
      for (int i = 0; i < 4; ++i)
        q[i] = pack2(ra[2*r + (i >> 1)][(i & 1) * 2], ra[2*r + (i >> 1)][(i & 1) * 2 + 1]);
      *reinterpret_cast<int4*>(&As[buf][row][k0]) =
          make_int4((int)q[0], (int)q[1], (int)q[2], (int)q[3]);
      *reinterpret_cast<int4*>(&Bs[buf][row][k0]) = rb[r];
    }
  };

  f32x4 acc[4][4] = {};
  {
    float4 ra[4]; int4 rb[2];
    ld(0, ra, rb);
    st(0, ra, rb);
  }
  __syncthreads();
  const int KT = KK / BK;
  for (int kt = 0; kt < KT; ++kt){
    int cur = kt & 1;
    float4 na[4]; int4 nb[2];
    if (kt + 1 < KT) ld(kt + 1, na, nb);
    bf16x8 af[4], bfr[4];
    #pragma unroll
    for (int i = 0; i < 4; ++i)
      af[i] = *reinterpret_cast<const bf16x8*>(&As[cur][wm*64 + i*16 + lr][lk]);
    #pragma unroll
    for (int i = 0; i < 4; ++i)
      bfr[i] = *reinterpret_cast<const bf16x8*>(&Bs[cur][wn*64 + i*16 + lr][lk]);
    #pragma unroll
    for (int i = 0; i < 4; ++i)
      #pragma unroll
      for (int j = 0; j < 4; ++j)
        acc[i][j] = __builtin_amdgcn_mfma_f32_16x16x32_bf16(af[i], bfr[j], acc[i][j], 0, 0, 0);
    if (kt + 1 < KT) st(cur ^ 1, na, nb);
    __syncthreads();
  }
  const int cm = mt * BM + wm * 64;
  const int cn = nt * BN + wn * 64;
  float bv[4];
  #pragma unroll
  for (int j = 0; j < 4; ++j) bv[j] = Bias[cn + j*16 + lr];
  #pragma unroll
  for (int i = 0; i < 4; ++i)
    #pragma unroll
    for (int j = 0; j < 4; ++j)
      #pragma unroll
      for (int r = 0; r < 4; ++r){
        size_t rr = (size_t)(cm + i*16 + (lane >> 4)*4 + r);
        C[rr * NN + (cn + j*16 + lr)] = acc[i][j][r] + bv[j];
      }
}

extern "C" void kernel_launch(void* const* d_in, const int* in_sizes, int n_in,
                              void* d_out, int out_size, void* d_ws, size_t ws_size,
                              hipStream_t stream){
  const float* x    = (const float*)d_in[0];   // fp32 [M][K] (fp16 ref -> float)
  const int*   w    = (const int*)d_in[1];     // [N][K/2] packed bytes
  const float* s    = (const float*)d_in[2];   // fp32 [N][NG]
  const float* bias = (const float*)d_in[3];   // fp32 [N]
  float* out = (float*)d_out;                  // fp32 [M][N]
  const int M = in_sizes[0] / KK;              // 8192
  const size_t needW = (size_t)NN * KK * 2;    // 90.2 MB for bf16 W
  const size_t needA = (size_t)M * KK * 2;     // 67.1 MB for bf16 x
  const int dq_blocks = (NN * (KK / 8)) / 256;

  if (ws_size >= needW + needA){
    unsigned short* wb = (unsigned short*)d_ws;
    unsigned short* xb = (unsigned short*)((char*)d_ws + needW);
    k_dequant<<<dq_blocks, 256, 0, stream>>>(w, s, wb);
    k_cvtA<<<(M * (KK / 8)) / 256, 256, 0, stream>>>(x, xb);
    if ((M % BM2) == 0){
      const int grid8 = (M / BM2) * (NN / BN2);     // 32*43 = 1376
      k_gemm8<<<grid8, 512, 0, stream>>>(xb, wb, bias, out);
    } else {
      const int grid = (M / BM) * (NN / BN);
      k_gemm_fast<<<grid, 256, 0, stream>>>(xb, wb, bias, out);
    }
  } else {
    unsigned short* wb = (unsigned short*)d_ws;
    k_dequant<<<dq_blocks, 256, 0, stream>>>(w, s, wb);
    const int grid = (M / BM) * (NN / BN);
    k_gemm_ws<<<grid, 256, 0, stream>>>(x, wb, bias, out);
  }
}

// Round 9
// 730.390 us; speedup vs baseline: 1.8563x; 1.0029x over previous
//
#include <hip/hip_runtime.h>

#define DEVINL __device__ __forceinline__

typedef __bf16 bf16x8 __attribute__((ext_vector_type(8)));
typedef float  f32x4  __attribute__((ext_vector_type(4)));

constexpr int KK = 4096;        // K
constexpr int NN = 11008;       // N
constexpr int NG = 32;          // K / group_size(128)

DEVINL unsigned short f2bf(float f){
  union { float f; unsigned u; } v; v.f = f;
  unsigned r = v.u + 0x7FFF + ((v.u >> 16) & 1);   // RNE; inputs finite here
  return (unsigned short)(r >> 16);
}
DEVINL unsigned pack2(float lo, float hi){
  return (unsigned)f2bf(lo) | ((unsigned)f2bf(hi) << 16);
}
DEVINL void gload16(const void* g, void* l){
  __builtin_amdgcn_global_load_lds(
      (const __attribute__((address_space(1))) void*)g,
      (__attribute__((address_space(3))) void*)l, 16, 0, 0);
}

// ---------------- pre-kernel 1: dequant W (int4-in-int32) -> bf16 [N][K] --
__global__ __launch_bounds__(256) void k_dequant(const int* __restrict__ W,
                                                 const float* __restrict__ S,
                                                 unsigned short* __restrict__ WB){
  int t = blockIdx.x * 256 + threadIdx.x;     // quad id; total NN*(KK/8)
  int row = t >> 9;                           // 512 quads per N-row
  int kp0 = (t & 511) << 2;
  int g   = kp0 >> 6;
  float s = S[row * NG + g];
  const int4 p = reinterpret_cast<const int4*>(W)[t];
  const int* pb = reinterpret_cast<const int*>(&p);
  unsigned q[4];
  #pragma unroll
  for (int i = 0; i < 4; ++i){
    int b = pb[i];
    float lo = ((float)(b & 15)        - 8.0f) * s;
    float hi = ((float)((b >> 4) & 15) - 8.0f) * s;
    q[i] = pack2(lo, hi);
  }
  reinterpret_cast<int4*>(WB)[t] = make_int4((int)q[0], (int)q[1], (int)q[2], (int)q[3]);
}

// ---------------- pre-kernel 2: convert x fp32 -> bf16 [M][K] -------------
__global__ __launch_bounds__(256) void k_cvtA(const float* __restrict__ X,
                                              unsigned short* __restrict__ XB){
  int t = blockIdx.x * 256 + threadIdx.x;
  const float4* src = reinterpret_cast<const float4*>(X) + (size_t)t * 2;
  float4 a = src[0], b = src[1];
  reinterpret_cast<int4*>(XB)[t] = make_int4(
      (int)pack2(a.x, a.y), (int)pack2(a.z, a.w),
      (int)pack2(b.x, b.y), (int)pack2(b.z, b.w));
}

// =================== 256x256 GEMM, 16 waves, 1 barrier/K-tile =============
// R9: 1024 thr = 16 waves (4m x 4n), per-wave 64x64 output. Each wave reads
// exactly ONE A-half and ONE B-half per K-tile -> no quadrant phases, one
// barrier + one vmcnt drain per tile. Waves drain the LDS read queue
// staggered, so MFMA overlaps LDS service (R8 was lockstep: sum not max).
// VGPR cap 128/wave at 16 waves/CU -> ks-split fragments (32 live frag regs).
constexpr int BM2 = 256, BN2 = 256, BK2 = 64;
constexpr int HBY = 16384;      // half-tile bytes (128 rows x 64 K x bf16)
constexpr int BUFBY = 65536;    // one dbuf buffer (A0,A1,B0,B1)

#define WAIT0  asm volatile("s_waitcnt vmcnt(0)" ::: "memory")
#define WAIT4  asm volatile("s_waitcnt vmcnt(4)" ::: "memory")
#define BAR()  do { __builtin_amdgcn_s_barrier(); asm volatile("" ::: "memory"); } while (0)

__global__ __launch_bounds__(1024, 1) void k_gemm16(const unsigned short* __restrict__ A,
                                                    const unsigned short* __restrict__ B,
                                                    const float* __restrict__ Bias,
                                                    float* __restrict__ C){
  __shared__ char smem[131072];
  const int tid = threadIdx.x, lane = tid & 63, wid = tid >> 6;   // wid 0..15
  const int wm = wid >> 2, wn = wid & 3;       // 4 x 4 waves
  const int lr = lane & 15, hi = lane >> 4;
  // XCD-aware swizzle: grid = 1376, divisible by 8.
  const int cpx = gridDim.x >> 3;
  const int wg  = (blockIdx.x & 7) * cpx + (blockIdx.x >> 3);
  const int NTT = NN / BN2;                    // 43
  const int mt = wg / NTT, nt = wg % NTT;
  const char* Ab = (const char*)(A + (size_t)mt * BM2 * KK);
  const char* Bb = (const char*)(B + (size_t)nt * BN2 * KK);
  const int srow  = tid >> 3;                  // staging row (0..127)
  const int scolb = (tid & 7) * 16;            // staging col byte (0..112)

  // Stage one half-tile (sel: 0=A0,1=A1,2=B0,3=B1): 1 gload16 per thread.
  auto stage_half = [&](int buf, int sel, int kt){
    const char* base = ((sel >= 2) ? Bb : Ab) + (size_t)((sel & 1) * 128) * KK * 2;
    const char* src = base + (size_t)srow * (KK * 2) + kt * (BK2 * 2)
                    + (scolb ^ ((srow & 7) << 4));           // inverse-swizzled src
    char* dst = smem + buf * BUFBY + sel * HBY + tid * 16;   // linear dst
    gload16(src, dst);
  };
  // Swizzled LDS fragment read (16B).
  auto frag = [&](int buf, int sel, int row, int bcol) -> bf16x8 {
    return *reinterpret_cast<const bf16x8*>(
        smem + buf * BUFBY + sel * HBY + row * 128 + (bcol ^ ((row & 7) << 4)));
  };

  const int selA = wm >> 1;                    // this wave's A-half
  const int rA0  = (wm & 1) * 64;              // row base within half
  const int selB = 2 + (wn >> 1);              // this wave's B-half
  const int cB0  = (wn & 1) * 64;              // col base within half

  f32x4 acc[4][4] = {};

  // Prologue: stage all 4 halves of K-tile 0, drain, barrier.
  stage_half(0, 0, 0); stage_half(0, 1, 0);
  stage_half(0, 2, 0); stage_half(0, 3, 0);
  WAIT0;
  BAR();

  const int NT = KK / BK2;                     // 64 K-tiles
  for (int t = 0; t < NT; ++t){
    const int buf = t & 1;
    const bool pf = (t + 1 < NT);
    if (pf){                                   // issue next-tile stages first:
      stage_half(buf ^ 1, 0, t + 1);           // ~full tile body (~3000 cyc)
      stage_half(buf ^ 1, 1, t + 1);           // covers the HBM/L2 latency
      stage_half(buf ^ 1, 2, t + 1);           // before the WAIT0 below.
      stage_half(buf ^ 1, 3, t + 1);
    }
    #pragma unroll
    for (int ks = 0; ks < 2; ++ks){            // ks-split keeps frags at 32 VGPR
      bf16x8 af[4], bf[4];
      #pragma unroll
      for (int i = 0; i < 4; ++i)
        af[i] = frag(buf, selA, rA0 + i*16 + lr, ks*64 + hi*16);
      #pragma unroll
      for (int j = 0; j < 4; ++j)
        bf[j] = frag(buf, selB, cB0 + j*16 + lr, ks*64 + hi*16);
      __builtin_amdgcn_s_setprio(1);
      #pragma unroll
      for (int i = 0; i < 4; ++i)
        #pragma unroll
        for (int j = 0; j < 4; ++j)
          acc[i][j] = __builtin_amdgcn_mfma_f32_16x16x32_bf16(af[i], bf[j], acc[i][j], 0, 0, 0);
      __builtin_amdgcn_s_setprio(0);
    }
    if (pf) WAIT0;                             // own 4 stages landed (issued ~1 tile ago)
    BAR();                                     // all waves: staged data global, reads done
  }

  // Epilogue: bias + fp32 store.
  const int cmb = mt * BM2, cnb = nt * BN2;
  #pragma unroll
  for (int j = 0; j < 4; ++j){
    int col = cnb + wn * 64 + j * 16 + lr;
    float bv = Bias[col];
    #pragma unroll
    for (int i = 0; i < 4; ++i){
      int row0 = cmb + wm * 64 + i * 16 + hi * 4;
      #pragma unroll
      for (int r = 0; r < 4; ++r)
        C[(size_t)(row0 + r) * NN + col] = acc[i][j][r] + bv;
    }
  }
}

// ---------------- fallback (verified round 8): 8-wave 256x256 -------------
#define R8WAIT4  asm volatile("s_waitcnt vmcnt(4)" ::: "memory")
__global__ __launch_bounds__(512, 2) void k_gemm8(const unsigned short* __restrict__ A,
                                                  const unsigned short* __restrict__ B,
                                                  const float* __restrict__ Bias,
                                                  float* __restrict__ C){
  __shared__ char smem[131072];
  const int tid = threadIdx.x, lane = tid & 63, wid = tid >> 6;
  const int wm = wid >> 2, wn = wid & 3;
  const int lr = lane & 15, hi = lane >> 4;
  const int cpx = gridDim.x >> 3;
  const int wg  = (blockIdx.x & 7) * cpx + (blockIdx.x >> 3);
  const int NTT = NN / BN2;
  const int mt = wg / NTT, nt = wg % NTT;
  const char* Ab = (const char*)(A + (size_t)mt * BM2 * KK);
  const char* Bb = (const char*)(B + (size_t)nt * BN2 * KK);
  const int srow  = tid >> 3;
  const int scolb = (tid & 7) * 16;

  auto stage_half = [&](int buf, int sel, int kt){
    const char* base = ((sel >= 2) ? Bb : Ab) + (size_t)((sel & 1) * 128) * KK * 2;
    #pragma unroll
    for (int r = 0; r < 2; ++r){
      int row = r * 64 + srow;
      const char* src = base + (size_t)row * (KK * 2) + kt * (BK2 * 2)
                      + (scolb ^ ((row & 7) << 4));
      char* dst = smem + buf * BUFBY + sel * HBY + r * 8192 + tid * 16;
      gload16(src, dst);
    }
  };
  auto frag = [&](int buf, int sel, int row, int bcol) -> bf16x8 {
    return *reinterpret_cast<const bf16x8*>(
        smem + buf * BUFBY + sel * HBY + row * 128 + (bcol ^ ((row & 7) << 4)));
  };

  f32x4 acc[8][4] = {};
  bf16x8 af[4][2], bf0[2][2], bf1[2][2];

  auto read_A = [&](int buf, int ha){
    #pragma unroll
    for (int i = 0; i < 4; ++i)
      #pragma unroll
      for (int ks = 0; ks < 2; ++ks)
        af[i][ks] = frag(buf, ha, wm*64 + i*16 + lr, ks*64 + hi*16);
  };
  auto read_B = [&](int buf, int hb, bf16x8 (&bf)[2][2]){
    #pragma unroll
    for (int j = 0; j < 2; ++j)
      #pragma unroll
      for (int ks = 0; ks < 2; ++ks)
        bf[j][ks] = frag(buf, 2 + hb, wn*32 + j*16 + lr, ks*64 + hi*16);
  };
  auto mfma16 = [&](const bf16x8 (&bf)[2][2], int HA, int HB){
    __builtin_amdgcn_s_setprio(1);
    #pragma unroll
    for (int i = 0; i < 4; ++i)
      #pragma unroll
      for (int j = 0; j < 2; ++j)
        #pragma unroll
        for (int ks = 0; ks < 2; ++ks)
          acc[HA*4 + i][HB*2 + j] = __builtin_amdgcn_mfma_f32_16x16x32_bf16(
              af[i][ks], bf[j][ks], acc[HA*4 + i][HB*2 + j], 0, 0, 0);
    __builtin_amdgcn_s_setprio(0);
  };

  stage_half(0, 0, 0); stage_half(0, 2, 0); stage_half(0, 3, 0); stage_half(0, 1, 0);
  R8WAIT4;
  BAR();

  const int NT = KK / BK2;
  for (int t = 0; t < NT; ++t){
    const int buf = t & 1;
    const bool pf = (t + 1 < NT);
    read_A(buf, 0);
    read_B(buf, 0, bf0);
    if (pf){ stage_half(buf ^ 1, 0, t + 1); stage_half(buf ^ 1, 2, t + 1); }
    if (pf) R8WAIT4; else WAIT0;
    BAR();
    read_B(buf, 1, bf1);
    mfma16(bf0, 0, 0);
    mfma16(bf1, 0, 1);
    read_A(buf, 1);
    if (pf){ stage_half(buf ^ 1, 3, t + 1); stage_half(buf ^ 1, 1, t + 1); }
    mfma16(bf1, 1, 1);
    mfma16(bf0, 1, 0);
    if (pf) R8WAIT4;
    BAR();
  }

  const int cmb = mt * BM2, cnb = nt * BN2;
  #pragma unroll
  for (int j = 0; j < 4; ++j){
    int col = cnb + (j >> 1) * 128 + wn * 32 + (j & 1) * 16 + lr;
    float bv = Bias[col];
    #pragma unroll
    for (int i = 0; i < 8; ++i){
      int row0 = cmb + (i >> 2) * 128 + wm * 64 + (i & 3) * 16 + hi * 4;
      #pragma unroll
      for (int r = 0; r < 4; ++r)
        C[(size_t)(row0 + r) * NN + col] = acc[i][j][r] + bv;
    }
  }
}

// ---------------- fallback (verified round 3): A fp32, reg-staged ---------
constexpr int BM = 128, BN = 128, BK = 32;
__global__ __launch_bounds__(256) void k_gemm_ws(const float* __restrict__ A,
                                                 const unsigned short* __restrict__ B,
                                                 const float* __restrict__ Bias,
                                                 float* __restrict__ C){
  __shared__ unsigned short As[2][BM][BK];
  __shared__ unsigned short Bs[2][BN][BK];
  const int tid = threadIdx.x;
  const int NT = NN / BN;
  const int mt = blockIdx.x / NT, nt = blockIdx.x % NT;
  const float*          Ab = A + (size_t)mt * BM * KK;
  const unsigned short* Bb = B + (size_t)nt * BN * KK;
  const int lane = tid & 63, wid = tid >> 6;
  const int wm = wid >> 1, wn = wid & 1;
  const int lr = lane & 15, lk = (lane >> 4) << 3;

  auto ld = [&](int kt, float4* ra, int4* rb){
    #pragma unroll
    for (int r = 0; r < 2; ++r){
      int c = r * 256 + tid, row = c >> 2, k0 = (c & 3) << 3;
      const float* src = Ab + (size_t)row * KK + kt * BK + k0;
      ra[2*r]   = *reinterpret_cast<const float4*>(src);
      ra[2*r+1] = *reinterpret_cast<const float4*>(src + 4);
      rb[r] = *reinterpret_cast<const int4*>(Bb + (size_t)row * KK + kt * BK + k0);
    }
  };
  auto st = [&](int buf, const float4* ra, const int4* rb){
    #pragma unroll
    for (int r = 0; r < 2; ++r){
      int c = r * 256 + tid, row = c >> 2, k0 = (c & 3) << 3;
      unsigned q[4];
      #pragma unroll
      for (int i = 0; i < 4; ++i)
        q[i] = pack2(ra[2*r + (i >> 1)][(i & 1) * 2], ra[2*r + (i >> 1)][(i & 1) * 2 + 1]);
      *reinterpret_cast<int4*>(&As[buf][row][k0]) =
          make_int4((int)q[0], (int)q[1], (int)q[2], (int)q[3]);
      *reinterpret_cast<int4*>(&Bs[buf][row][k0]) = rb[r];
    }
  };

  f32x4 acc[4][4] = {};
  {
    float4 ra[4]; int4 rb[2];
    ld(0, ra, rb);
    st(0, ra, rb);
  }
  __syncthreads();
  const int KT = KK / BK;
  for (int kt = 0; kt < KT; ++kt){
    int cur = kt & 1;
    float4 na[4]; int4 nb[2];
    if (kt + 1 < KT) ld(kt + 1, na, nb);
    bf16x8 af[4], bfr[4];
    #pragma unroll
    for (int i = 0; i < 4; ++i)
      af[i] = *reinterpret_cast<const bf16x8*>(&As[cur][wm*64 + i*16 + lr][lk]);
    #pragma unroll
    for (int i = 0; i < 4; ++i)
      bfr[i] = *reinterpret_cast<const bf16x8*>(&Bs[cur][wn*64 + i*16 + lr][lk]);
    #pragma unroll
    for (int i = 0; i < 4; ++i)
      #pragma unroll
      for (int j = 0; j < 4; ++j)
        acc[i][j] = __builtin_amdgcn_mfma_f32_16x16x32_bf16(af[i], bfr[j], acc[i][j], 0, 0, 0);
    if (kt + 1 < KT) st(cur ^ 1, na, nb);
    __syncthreads();
  }
  const int cm = mt * BM + wm * 64;
  const int cn = nt * BN + wn * 64;
  float bv[4];
  #pragma unroll
  for (int j = 0; j < 4; ++j) bv[j] = Bias[cn + j*16 + lr];
  #pragma unroll
  for (int i = 0; i < 4; ++i)
    #pragma unroll
    for (int j = 0; j < 4; ++j)
      #pragma unroll
      for (int r = 0; r < 4; ++r){
        size_t rr = (size_t)(cm + i*16 + (lane >> 4)*4 + r);
        C[rr * NN + (cn + j*16 + lr)] = acc[i][j][r] + bv[j];
      }
}

extern "C" void kernel_launch(void* const* d_in, const int* in_sizes, int n_in,
                              void* d_out, int out_size, void* d_ws, size_t ws_size,
                              hipStream_t stream){
  const float* x    = (const float*)d_in[0];   // fp32 [M][K] (fp16 ref -> float)
  const int*   w    = (const int*)d_in[1];     // [N][K/2] packed bytes
  const float* s    = (const float*)d_in[2];   // fp32 [N][NG]
  const float* bias = (const float*)d_in[3];   // fp32 [N]
  float* out = (float*)d_out;                  // fp32 [M][N]
  const int M = in_sizes[0] / KK;              // 8192
  const size_t needW = (size_t)NN * KK * 2;    // 90.2 MB for bf16 W
  const size_t needA = (size_t)M * KK * 2;     // 67.1 MB for bf16 x
  const int dq_blocks = (NN * (KK / 8)) / 256;

  if (ws_size >= needW + needA){
    unsigned short* wb = (unsigned short*)d_ws;
    unsigned short* xb = (unsigned short*)((char*)d_ws + needW);
    k_dequant<<<dq_blocks, 256, 0, stream>>>(w, s, wb);
    k_cvtA<<<(M * (KK / 8)) / 256, 256, 0, stream>>>(x, xb);
    if ((M % BM2) == 0){
      const int grid8 = (M / BM2) * (NN / BN2);     // 32*43 = 1376
      k_gemm16<<<grid8, 1024, 0, stream>>>(xb, wb, bias, out);
    } else {
      const int grid8 = ((M + BM2 - 1) / BM2) * (NN / BN2);
      (void)grid8;
      const int grid = (M / BM) * (NN / BN);
      k_gemm_ws<<<grid, 256, 0, stream>>>(x, wb, bias, out);
    }
  } else {
    unsigned short* wb = (unsigned short*)d_ws;
    k_dequant<<<dq_blocks, 256, 0, stream>>>(w, s, wb);
    const int grid = (M / BM) * (NN / BN);
    k_gemm_ws<<<grid, 256, 0, stream>>>(x, wb, bias, out);
  }
}